// Round 15
// baseline (338.148 us; speedup 1.0000x reference)
//
#include <hip/hip_runtime.h>
#include <hip/hip_fp16.h>

#define N_NODES 50000
#define N_EDGES 800000
#define NB_SCAN 49          // ceil(50000 / 1024)
#define DEG_PAD (NB_SCAN * 1024)   // 50176, zero-padded so int4 loads are unguarded
#define NBKT 196            // ceil(50000 / 256) coarse buckets (dst >> 8)
#define EPB_BIN 4096        // edges per k_bin block
#define NB_BIN ((N_EDGES + EPB_BIN - 1) / EPB_BIN)   // 196

static __device__ __forceinline__ float lrelu(float x) { return fmaxf(x, 0.2f * x); }
static __device__ __forceinline__ float to_f(float x) { return x; }
static __device__ __forceinline__ float to_f(__half x) { return __half2float(x); }

// ---------------- CSR build ----------------
__global__ void k_count(const int* __restrict__ dst, int* __restrict__ deg) {
    int e = blockIdx.x * blockDim.x + threadIdx.x;
    if (e < N_EDGES) atomicAdd(&deg[dst[e]], 1);
}

__global__ void __launch_bounds__(256) k_scanA(const int* __restrict__ deg,
                                               int* __restrict__ bsum) {
    const int t = threadIdx.x;
    const int b = blockIdx.x;
    const int base = (b * 256 + t) * 4;
    const int4 v = *reinterpret_cast<const int4*>(deg + base);  // padded: safe
    int s = v.x + v.y + v.z + v.w;
#pragma unroll
    for (int off = 32; off > 0; off >>= 1) s += __shfl_down(s, off);
    __shared__ int ws[4];
    if ((t & 63) == 0) ws[t >> 6] = s;
    __syncthreads();
    if (t == 0) bsum[b] = ws[0] + ws[1] + ws[2] + ws[3];
}

__global__ void __launch_bounds__(64) k_scanB(const int* __restrict__ bsum,
                                              int* __restrict__ boff,
                                              int* __restrict__ rowp) {
    const int t = threadIdx.x;
    const int v = (t < NB_SCAN) ? bsum[t] : 0;
    int inc = v;
#pragma unroll
    for (int off = 1; off < 64; off <<= 1) {
        const int u = __shfl_up(inc, off);
        if (t >= off) inc += u;
    }
    if (t < NB_SCAN) boff[t] = inc - v;
    if (t == 0) rowp[N_NODES] = N_EDGES;
}

__global__ void __launch_bounds__(256) k_scanC(const int* __restrict__ deg,
                                               const int* __restrict__ boff,
                                               int* __restrict__ rowp) {
    const int t = threadIdx.x;
    const int b = blockIdx.x;
    const int lane = t & 63;
    const int wv = t >> 6;
    const int base = (b * 256 + t) * 4;
    const int4 v = *reinterpret_cast<const int4*>(deg + base);
    const int s = v.x + v.y + v.z + v.w;
    int inc = s;
#pragma unroll
    for (int off = 1; off < 64; off <<= 1) {
        const int u = __shfl_up(inc, off);
        if (lane >= off) inc += u;
    }
    __shared__ int wsum[4];
    if (lane == 63) wsum[wv] = inc;
    __syncthreads();
    int add = boff[b];
    for (int w = 0; w < wv; ++w) add += wsum[w];
    const int exc = add + inc - s;
    if (base < N_NODES) rowp[base] = exc;
    if (base + 1 < N_NODES) rowp[base + 1] = exc + v.x;
    if (base + 2 < N_NODES) rowp[base + 2] = exc + v.x + v.y;
    if (base + 3 < N_NODES) rowp[base + 3] = exc + v.x + v.y + v.z;
}

// ---------------- binned scatter; stage entry = src(16b) | local(8b)<<16 -----
__global__ void __launch_bounds__(256) k_bin(const int* __restrict__ src,
                                             const int* __restrict__ dst,
                                             const int* __restrict__ rowp,
                                             int* __restrict__ bfill,
                                             unsigned int* __restrict__ stage) {
    __shared__ int lcnt[NBKT];
    __shared__ int gb[NBKT];
    __shared__ int lf[NBKT];
    const int t = threadIdx.x;
    const int e0 = blockIdx.x * EPB_BIN;
    for (int i = t; i < NBKT; i += 256) lcnt[i] = 0;
    __syncthreads();
    int dcache[16];
#pragma unroll
    for (int i = 0; i < 16; ++i) {
        const int e = e0 + i * 256 + t;
        if (e < N_EDGES) {
            const int d = dst[e];
            dcache[i] = d;
            atomicAdd(&lcnt[d >> 8], 1);
        } else dcache[i] = -1;
    }
    __syncthreads();
    for (int i = t; i < NBKT; i += 256) {
        gb[i] = rowp[i << 8] + atomicAdd(&bfill[i], lcnt[i]);
        lf[i] = 0;
    }
    __syncthreads();
#pragma unroll
    for (int i = 0; i < 16; ++i) {
        const int e = e0 + i * 256 + t;
        if (e < N_EDGES) {
            const int d = dcache[i];
            const int b = d >> 8;
            const int r = atomicAdd(&lf[b], 1);
            stage[gb[b] + r] = (unsigned int)src[e] | ((unsigned int)(d & 255) << 16);
        }
    }
}

__global__ void __launch_bounds__(256) k_bscatter(const unsigned int* __restrict__ stage,
                                                  const int* __restrict__ rowp,
                                                  int* __restrict__ col) {
    __shared__ int srow[257];
    __shared__ int lf[256];
    const int t = threadIdx.x;
    const int n0 = blockIdx.x << 8;
    for (int i = t; i < 257; i += 256) srow[i] = rowp[min(n0 + i, N_NODES)];
    lf[t] = 0;
    __syncthreads();
    const int base = srow[0], end = srow[256];
    for (int j = base + t; j < end; j += 256) {
        const unsigned int e = stage[j];
        const int local = (int)(e >> 16) & 255;
        const int pos = srow[local] + atomicAdd(&lf[local], 1);
        col[pos] = (int)(e & 0xFFFFu);
    }
}

// ---------------- el/er: el[n][h] = sum_k x[n,k]*Wa[k][h]; float4 [N][4] -----
template <int K, int F, typename XT>
__global__ void __launch_bounds__(256) k_el(const XT* __restrict__ x,
                                            const float* __restrict__ W,
                                            const float* __restrict__ al,
                                            const float* __restrict__ ar,
                                            float* __restrict__ el,
                                            float* __restrict__ er) {
    __shared__ float sWa[K * 3];
    __shared__ float sWr[K * 3];
    const int t = threadIdx.x;
    if (t < 3 * K) {
        const int h = t / K, k = t % K;
        float sa = 0.f, sr = 0.f;
        for (int f = 0; f < F; ++f) {
            const float w = W[k * 3 * F + h * F + f];
            sa += w * al[h * F + f];
            sr += w * ar[h * F + f];
        }
        sWa[k * 3 + h] = sa;
        sWr[k * 3 + h] = sr;
    }
    __syncthreads();
    const int n = blockIdx.x * 256 + t;
    if (n >= N_NODES) return;
    const XT* __restrict__ xr = x + (size_t)n * K;
    float a0 = 0.f, a1 = 0.f, a2 = 0.f, r0 = 0.f, r1 = 0.f, r2 = 0.f;
#pragma unroll 4
    for (int k = 0; k < K; ++k) {
        const float xv = to_f(xr[k]);
        a0 += xv * sWa[k * 3 + 0];
        a1 += xv * sWa[k * 3 + 1];
        a2 += xv * sWa[k * 3 + 2];
        r0 += xv * sWr[k * 3 + 0];
        r1 += xv * sWr[k * 3 + 1];
        r2 += xv * sWr[k * 3 + 2];
    }
    *reinterpret_cast<float4*>(el + (size_t)n * 4) = make_float4(a0, a1, a2, 0.f);
    *reinterpret_cast<float4*>(er + (size_t)n * 4) = make_float4(r0, r1, r2, 0.f);
}

// ---------------- L1 aggregation over INPUT features (K=9, fp32) -------------
__global__ void __launch_bounds__(256) k_aggw9(const float* __restrict__ x,
                                               const float* __restrict__ el,
                                               const float* __restrict__ er,
                                               const int* __restrict__ rowp,
                                               const int* __restrict__ col,
                                               float* __restrict__ agg) {
    const int wv = threadIdx.x >> 6;
    const int lane = threadIdx.x & 63;
    const int n = blockIdx.x * 4 + wv;          // grid exact
    const int jb = rowp[n], je = rowp[n + 1];

    __shared__ float wbuf[4][3][68];
    const float4 er4 = *reinterpret_cast<const float4*>(er + (size_t)n * 4);
    const int h = lane < 27 ? lane / 9 : 0;
    const int k = lane < 27 ? lane % 9 : 0;
    float acc = 0.f;
    float sw0 = 0.f, sw1 = 0.f, sw2 = 0.f;

    for (int c0 = jb; c0 < je; c0 += 64) {
        const int cnt = min(64, je - c0);
        float w0 = 0.f, w1 = 0.f, w2 = 0.f;
        if (lane < cnt) {
            const int s = col[c0 + lane];
            const float4 e4 = *reinterpret_cast<const float4*>(el + (size_t)s * 4);
            w0 = __expf(lrelu(e4.x + er4.x));
            w1 = __expf(lrelu(e4.y + er4.y));
            w2 = __expf(lrelu(e4.z + er4.z));
            wbuf[wv][0][lane] = w0;
            wbuf[wv][1][lane] = w1;
            wbuf[wv][2][lane] = w2;
        }
        sw0 += w0; sw1 += w1; sw2 += w2;
        if (lane < 27) {
            const float* __restrict__ wrow = &wbuf[wv][h][0];
            int e = 0;
            for (; e + 4 <= cnt; e += 4) {
                const int sA = __builtin_amdgcn_readfirstlane(col[c0 + e + 0]);
                const int sB = __builtin_amdgcn_readfirstlane(col[c0 + e + 1]);
                const int sC = __builtin_amdgcn_readfirstlane(col[c0 + e + 2]);
                const int sD = __builtin_amdgcn_readfirstlane(col[c0 + e + 3]);
                const float xA = x[(size_t)sA * 9 + k];
                const float xB = x[(size_t)sB * 9 + k];
                const float xC = x[(size_t)sC * 9 + k];
                const float xD = x[(size_t)sD * 9 + k];
                acc += wrow[e + 0] * xA + wrow[e + 1] * xB
                     + wrow[e + 2] * xC + wrow[e + 3] * xD;
            }
            for (; e < cnt; ++e) {
                const int s = __builtin_amdgcn_readfirstlane(col[c0 + e]);
                acc += wrow[e] * x[(size_t)s * 9 + k];
            }
        }
    }
#pragma unroll
    for (int off = 32; off > 0; off >>= 1) {
        sw0 += __shfl_xor(sw0, off);
        sw1 += __shfl_xor(sw1, off);
        sw2 += __shfl_xor(sw2, off);
    }
    if (lane < 27) {
        const float swh = (h == 0) ? sw0 : (h == 1 ? sw1 : sw2);
        agg[(size_t)n * 28 + lane] = (je > jb) ? acc / swh : 0.f;
    }
    if (lane == 27) agg[(size_t)n * 28 + 27] = 0.f;
}

// ---------------- L2 aggregation: 2 edges/gather (half-wave per edge) --------
// Lane l: edge parity p=l>>5, features f0=2*(l&31), f0+1 (one dword = __half2).
// One gather instruction fetches two 128B rows. Cols cached in LDS from phase1.
__global__ void __launch_bounds__(256) k_aggw64(const __half* __restrict__ x,
                                                const float* __restrict__ el,
                                                const float* __restrict__ er,
                                                const int* __restrict__ rowp,
                                                const int* __restrict__ col,
                                                __half* __restrict__ agg) {
    const int wv = threadIdx.x >> 6;
    const int lane = threadIdx.x & 63;
    const int n = blockIdx.x * 4 + wv;          // grid exact
    const int jb = rowp[n], je = rowp[n + 1];

    __shared__ float wbuf[4][3][68];
    __shared__ int cbuf[4][68];
    const float4 er4 = *reinterpret_cast<const float4*>(er + (size_t)n * 4);
    const int p = lane >> 5;                    // edge parity
    const int f0 = (lane & 31) * 2;             // feature pair base
    // acc[f][h]: f in {0,1} (features f0, f0+1), h in {0,1,2}
    float a00 = 0.f, a01 = 0.f, a02 = 0.f;
    float a10 = 0.f, a11 = 0.f, a12 = 0.f;
    float sw0 = 0.f, sw1 = 0.f, sw2 = 0.f;

    for (int c0 = jb; c0 < je; c0 += 64) {
        const int cnt = min(64, je - c0);
        float w0 = 0.f, w1 = 0.f, w2 = 0.f;
        if (lane < cnt) {
            const int s = col[c0 + lane];
            cbuf[wv][lane] = s;
            const float4 e4 = *reinterpret_cast<const float4*>(el + (size_t)s * 4);
            w0 = __expf(lrelu(e4.x + er4.x));
            w1 = __expf(lrelu(e4.y + er4.y));
            w2 = __expf(lrelu(e4.z + er4.z));
            wbuf[wv][0][lane] = w0;
            wbuf[wv][1][lane] = w1;
            wbuf[wv][2][lane] = w2;
        }
        sw0 += w0; sw1 += w1; sw2 += w2;
        int e = 0;
        for (; e + 2 <= cnt; e += 2) {
            const int ei = e + p;
            const int s = cbuf[wv][ei];
            const float2 xv = __half22float2(
                *reinterpret_cast<const __half2*>(x + (size_t)s * 64 + f0));
            const float we0 = wbuf[wv][0][ei];
            const float we1 = wbuf[wv][1][ei];
            const float we2 = wbuf[wv][2][ei];
            a00 += we0 * xv.x; a01 += we1 * xv.x; a02 += we2 * xv.x;
            a10 += we0 * xv.y; a11 += we1 * xv.y; a12 += we2 * xv.y;
        }
        if (e < cnt && p == 0) {               // odd tail: lanes 0..31 only
            const int s = cbuf[wv][e];
            const float2 xv = __half22float2(
                *reinterpret_cast<const __half2*>(x + (size_t)s * 64 + f0));
            const float we0 = wbuf[wv][0][e];
            const float we1 = wbuf[wv][1][e];
            const float we2 = wbuf[wv][2][e];
            a00 += we0 * xv.x; a01 += we1 * xv.x; a02 += we2 * xv.x;
            a10 += we0 * xv.y; a11 += we1 * xv.y; a12 += we2 * xv.y;
        }
    }
    // combine edge parities (features are disjoint per lane pair l, l+32)
    a00 += __shfl_xor(a00, 32); a01 += __shfl_xor(a01, 32); a02 += __shfl_xor(a02, 32);
    a10 += __shfl_xor(a10, 32); a11 += __shfl_xor(a11, 32); a12 += __shfl_xor(a12, 32);
#pragma unroll
    for (int off = 32; off > 0; off >>= 1) {
        sw0 += __shfl_xor(sw0, off);
        sw1 += __shfl_xor(sw1, off);
        sw2 += __shfl_xor(sw2, off);
    }
    if (lane < 32) {
        __half* __restrict__ ao = agg + (size_t)n * 192;
        if (je > jb) {
            const float i0 = 1.f / sw0, i1 = 1.f / sw1, i2 = 1.f / sw2;
            *reinterpret_cast<__half2*>(ao + f0) =
                __floats2half2_rn(a00 * i0, a10 * i0);
            *reinterpret_cast<__half2*>(ao + 64 + f0) =
                __floats2half2_rn(a01 * i1, a11 * i1);
            *reinterpret_cast<__half2*>(ao + 128 + f0) =
                __floats2half2_rn(a02 * i2, a12 * i2);
        } else {
            const __half2 z = __floats2half2_rn(0.f, 0.f);
            *reinterpret_cast<__half2*>(ao + f0) = z;
            *reinterpret_cast<__half2*>(ao + 64 + f0) = z;
            *reinterpret_cast<__half2*>(ao + 128 + f0) = z;
        }
    }
}

// ---------------- post-agg GEMM (fp32 agg, layer 1) --------------------------
template <int KE, int AS, int HOFF>
__global__ void __launch_bounds__(192) k_gemm2(const float* __restrict__ agg,
                                               const float* __restrict__ W,
                                               const float* __restrict__ bias,
                                               __half* __restrict__ hout) {
    const int NPB = 16;
    const int h = threadIdx.x >> 6;
    const int c = threadIdx.x & 63;
    float wreg[KE];
#pragma unroll
    for (int k = 0; k < KE; ++k) wreg[k] = W[k * 192 + h * 64 + c];

    __shared__ float At[NPB * AS];
    __shared__ float part[3][NPB][64];
    const int nbase = blockIdx.x * NPB;         // 3125 * 16 = 50000 exact

    const float4* __restrict__ src4 =
        reinterpret_cast<const float4*>(agg + (size_t)nbase * AS);
    float4* At4 = reinterpret_cast<float4*>(At);
    for (int idx = threadIdx.x; idx < NPB * AS / 4; idx += 192) At4[idx] = src4[idx];
    __syncthreads();

#pragma unroll
    for (int i = 0; i < NPB; ++i) {
        const float* __restrict__ ar = At + i * AS + h * HOFF;
        float acc = 0.f;
#pragma unroll
        for (int k = 0; k < KE; ++k) acc += ar[k] * wreg[k];
        part[h][i][c] = acc;
    }
    __syncthreads();
    for (int idx = threadIdx.x; idx < NPB * 64; idx += 192) {
        const int i = idx >> 6, cc = idx & 63;
        const float v = part[0][i][cc] + part[1][i][cc] + part[2][i][cc]
                      + bias[cc] + bias[64 + cc] + bias[128 + cc];
        hout[(size_t)(nbase + i) * 64 + cc] = __float2half(v);
    }
}

// ---------------- post-agg GEMM (fp16 agg staged->fp32 LDS, layer 2) ---------
// Identical fp32 inner loop to k_gemm2; conversion only at the staging copy.
__global__ void __launch_bounds__(192) k_gemm2s(const __half* __restrict__ agg,
                                                const float* __restrict__ W,
                                                const float* __restrict__ bias,
                                                __half* __restrict__ hout) {
    const int NPB = 16;
    const int h = threadIdx.x >> 6;
    const int c = threadIdx.x & 63;
    float wreg[64];
#pragma unroll
    for (int k = 0; k < 64; ++k) wreg[k] = W[k * 192 + h * 64 + c];

    __shared__ float At[NPB * 192];
    __shared__ float part[3][NPB][64];
    const int nbase = blockIdx.x * NPB;         // 3125 * 16 = 50000 exact

    const uint4* __restrict__ src4 =
        reinterpret_cast<const uint4*>(agg + (size_t)nbase * 192);
    for (int idx = threadIdx.x; idx < NPB * 192 / 8; idx += 192) {
        const uint4 q = src4[idx];
        const float2 f0 = __half22float2(*reinterpret_cast<const __half2*>(&q.x));
        const float2 f1 = __half22float2(*reinterpret_cast<const __half2*>(&q.y));
        const float2 f2 = __half22float2(*reinterpret_cast<const __half2*>(&q.z));
        const float2 f3 = __half22float2(*reinterpret_cast<const __half2*>(&q.w));
        *reinterpret_cast<float4*>(&At[idx * 8]) = make_float4(f0.x, f0.y, f1.x, f1.y);
        *reinterpret_cast<float4*>(&At[idx * 8 + 4]) = make_float4(f2.x, f2.y, f3.x, f3.y);
    }
    __syncthreads();

#pragma unroll 4
    for (int i = 0; i < NPB; ++i) {
        const float* __restrict__ ar = At + i * 192 + h * 64;
        float acc = 0.f;
#pragma unroll
        for (int k4 = 0; k4 < 16; ++k4) {
            const float4 a = *reinterpret_cast<const float4*>(ar + 4 * k4);
            acc += a.x * wreg[4 * k4 + 0] + a.y * wreg[4 * k4 + 1]
                 + a.z * wreg[4 * k4 + 2] + a.w * wreg[4 * k4 + 3];
        }
        part[h][i][c] = acc;
    }
    __syncthreads();
    for (int idx = threadIdx.x; idx < NPB * 64; idx += 192) {
        const int i = idx >> 6, cc = idx & 63;
        const float v = part[0][i][cc] + part[1][i][cc] + part[2][i][cc]
                      + bias[cc] + bias[64 + cc] + bias[128 + cc];
        hout[(size_t)(nbase + i) * 64 + cc] = __float2half(v);
    }
}

// ---------------- layer 3: feat3 = h @ W3 (64->6), h is fp16 -----------------
__global__ void __launch_bounds__(256) k_feat3(const __half* __restrict__ x,
                                               const float* __restrict__ W3,
                                               float* __restrict__ feat3) {
    __shared__ float Wl[64 * 6];
    __shared__ float xl[32 * 64];
    const int t = threadIdx.x;
    const int n0 = blockIdx.x * 32;
    const int nvalid = min(32, N_NODES - n0);
    for (int idx = t; idx < 384; idx += 256) Wl[idx] = W3[idx];
    for (int idx = t; idx < nvalid * 64; idx += 256)
        xl[idx] = __half2float(x[(size_t)n0 * 64 + idx]);
    __syncthreads();

    const int i = t >> 3;
    const int slot = t & 7;
    if (i < nvalid && slot < 6) {
        float acc = 0.f;
#pragma unroll
        for (int k4 = 0; k4 < 16; ++k4) {
            const float4 xv = *reinterpret_cast<const float4*>(&xl[i * 64 + 4 * k4]);
            acc += Wl[(4 * k4 + 0) * 6 + slot] * xv.x;
            acc += Wl[(4 * k4 + 1) * 6 + slot] * xv.y;
            acc += Wl[(4 * k4 + 2) * 6 + slot] * xv.z;
            acc += Wl[(4 * k4 + 3) * 6 + slot] * xv.w;
        }
        feat3[(size_t)(n0 + i) * 8 + slot] = acc;
    }
}

// ---------------- layer-3 aggregation: 8 lanes/node, inline weights ----------
__global__ void __launch_bounds__(256) k_agg3(const float* __restrict__ feat3,
                                              const float* __restrict__ el3,
                                              const float* __restrict__ er3,
                                              const float* __restrict__ b3,
                                              const int* __restrict__ rowp,
                                              const int* __restrict__ col,
                                              float* __restrict__ out) {
    const int t = blockIdx.x * blockDim.x + threadIdx.x;
    const int n = t >> 3;
    const int r = t & 7;       // feature slot (0..5 valid; head = r/2)
    if (n >= N_NODES) return;
    int hh = r >> 1; if (hh > 2) hh = 2;
    const float ern = er3[(size_t)n * 4 + hh];
    const int jb = rowp[n], je = rowp[n + 1];
    float a = 0.f, sw = 0.f;
    for (int j = jb; j < je; ++j) {
        const int s = col[j];
        const float w = __expf(lrelu(el3[(size_t)s * 4 + hh] + ern));
        const float f = feat3[(size_t)s * 8 + r];
        a += w * f;
        sw += w;
    }
    float v = (je > jb && r < 6) ? (a / sw) : 0.f;
    v += __shfl_down(v, 2, 8);
    v += __shfl_down(v, 4, 8);
    if (r < 2) {
        const float bc = b3[r] + b3[r + 2] + b3[r + 4];
        out[(size_t)n * 2 + r] = v + bc;
    }
}

extern "C" void kernel_launch(void* const* d_in, const int* in_sizes, int n_in,
                              void* d_out, int out_size, void* d_ws, size_t ws_size,
                              hipStream_t stream) {
    const float* feats = (const float*)d_in[0];
    const int* src = (const int*)d_in[1];
    const int* dst = (const int*)d_in[2];
    const float* W1 = (const float*)d_in[3];
    const float* al1 = (const float*)d_in[4];
    const float* ar1 = (const float*)d_in[5];
    const float* b1 = (const float*)d_in[6];
    const float* W2 = (const float*)d_in[7];
    const float* al2 = (const float*)d_in[8];
    const float* ar2 = (const float*)d_in[9];
    const float* b2 = (const float*)d_in[10];
    const float* W3 = (const float*)d_in[11];
    const float* al3 = (const float*)d_in[12];
    const float* ar3 = (const float*)d_in[13];
    const float* b3 = (const float*)d_in[14];
    float* out = (float*)d_out;

    char* ws = (char*)d_ws;
    size_t off = 0;
    auto alloc = [&](size_t bytes) {
        void* p = ws + off;
        off += (bytes + 255) & ~(size_t)255;
        return p;
    };
    float* agg = (float*)alloc((size_t)N_NODES * 28 * 4);        // L1 agg fp32 [N][28]
    __half* aggH = (__half*)alloc((size_t)N_NODES * 192 * 2);    // L2 agg fp16 [N][192]
    __half* hbufH = (__half*)alloc((size_t)N_NODES * 64 * 2);    // 6.4 MB fp16 hidden
    float* el = (float*)alloc((size_t)N_NODES * 4 * 4);
    float* er = (float*)alloc((size_t)N_NODES * 4 * 4);
    int* deg = (int*)alloc(((size_t)DEG_PAD + 256) * 4);         // deg + bfill, one memset
    int* bfill = deg + DEG_PAD;
    int* rowp = (int*)alloc((size_t)(N_NODES + 1) * 4);
    int* col = (int*)alloc((size_t)N_EDGES * 4);
    unsigned int* stage = (unsigned int*)alloc((size_t)N_EDGES * 4);  // packed 3.2 MB
    int* bsum = (int*)alloc(64 * 4);
    int* boff = (int*)alloc(64 * 4);
    float* feat3 = (float*)alloc((size_t)N_NODES * 8 * 4);
    (void)ws_size;

    // ---- CSR build ----
    hipMemsetAsync(deg, 0, ((size_t)DEG_PAD + 256) * 4, stream);
    int eb = (N_EDGES + 255) / 256;
    k_count<<<eb, 256, 0, stream>>>(dst, deg);
    k_scanA<<<NB_SCAN, 256, 0, stream>>>(deg, bsum);
    k_scanB<<<1, 64, 0, stream>>>(bsum, boff, rowp);
    k_scanC<<<NB_SCAN, 256, 0, stream>>>(deg, boff, rowp);
    k_bin<<<NB_BIN, 256, 0, stream>>>(src, dst, rowp, bfill, stage);
    k_bscatter<<<NBKT, 256, 0, stream>>>(stage, rowp, col);

    const int ab = N_NODES / 4;             // wave/node kernels: 4 waves/block
    const int gb2 = N_NODES / 16;           // k_gemm2*: 16 nodes/block (3125)
    const int nb = (N_NODES + 255) / 256;
    const int nb3 = (N_NODES + 31) / 32;

    // ---- layer 1: aggregate INPUT features (1.8 MB table), then GEMM -------
    k_el<9, 64, float><<<nb, 256, 0, stream>>>(feats, W1, al1, ar1, el, er);
    k_aggw9<<<ab, 256, 0, stream>>>(feats, el, er, rowp, col, agg);
    k_gemm2<9, 28, 9><<<gb2, 192, 0, stream>>>(agg, W1, b1, hbufH);

    // ---- layer 2: aggregate fp16 hidden (6.4 MB table), then GEMM ----------
    k_el<64, 64, __half><<<nb, 256, 0, stream>>>(hbufH, W2, al2, ar2, el, er);
    k_aggw64<<<ab, 256, 0, stream>>>(hbufH, el, er, rowp, col, aggH);
    k_gemm2s<<<gb2, 192, 0, stream>>>(aggH, W2, b2, hbufH);

    // ---- layer 3 ----
    k_el<64, 2, __half><<<nb, 256, 0, stream>>>(hbufH, W3, al3, ar3, el, er);
    k_feat3<<<nb3, 256, 0, stream>>>(hbufH, W3, feat3);
    k_agg3<<<nb3, 256, 0, stream>>>(feat3, el, er, b3, rowp, col, out);
}

// Round 16
// 315.528 us; speedup vs baseline: 1.0717x; 1.0717x over previous
//
#include <hip/hip_runtime.h>
#include <hip/hip_fp16.h>

#define N_NODES 50000
#define N_EDGES 800000
#define NB_SCAN 49          // ceil(50000 / 1024)
#define DEG_PAD (NB_SCAN * 1024)   // 50176, zero-padded so int4 loads are unguarded
#define NBKT 196            // ceil(50000 / 256) coarse buckets (dst >> 8)
#define EPB_BIN 4096        // edges per k_bin block
#define NB_BIN ((N_EDGES + EPB_BIN - 1) / EPB_BIN)   // 196

static __device__ __forceinline__ float lrelu(float x) { return fmaxf(x, 0.2f * x); }
static __device__ __forceinline__ float to_f(float x) { return x; }
static __device__ __forceinline__ float to_f(__half x) { return __half2float(x); }

// ---------------- CSR build ----------------
__global__ void k_count(const int* __restrict__ dst, int* __restrict__ deg) {
    int e = blockIdx.x * blockDim.x + threadIdx.x;
    if (e < N_EDGES) atomicAdd(&deg[dst[e]], 1);
}

__global__ void __launch_bounds__(256) k_scanA(const int* __restrict__ deg,
                                               int* __restrict__ bsum) {
    const int t = threadIdx.x;
    const int b = blockIdx.x;
    const int base = (b * 256 + t) * 4;
    const int4 v = *reinterpret_cast<const int4*>(deg + base);  // padded: safe
    int s = v.x + v.y + v.z + v.w;
#pragma unroll
    for (int off = 32; off > 0; off >>= 1) s += __shfl_down(s, off);
    __shared__ int ws[4];
    if ((t & 63) == 0) ws[t >> 6] = s;
    __syncthreads();
    if (t == 0) bsum[b] = ws[0] + ws[1] + ws[2] + ws[3];
}

__global__ void __launch_bounds__(64) k_scanB(const int* __restrict__ bsum,
                                              int* __restrict__ boff,
                                              int* __restrict__ rowp) {
    const int t = threadIdx.x;
    const int v = (t < NB_SCAN) ? bsum[t] : 0;
    int inc = v;
#pragma unroll
    for (int off = 1; off < 64; off <<= 1) {
        const int u = __shfl_up(inc, off);
        if (t >= off) inc += u;
    }
    if (t < NB_SCAN) boff[t] = inc - v;
    if (t == 0) rowp[N_NODES] = N_EDGES;
}

__global__ void __launch_bounds__(256) k_scanC(const int* __restrict__ deg,
                                               const int* __restrict__ boff,
                                               int* __restrict__ rowp) {
    const int t = threadIdx.x;
    const int b = blockIdx.x;
    const int lane = t & 63;
    const int wv = t >> 6;
    const int base = (b * 256 + t) * 4;
    const int4 v = *reinterpret_cast<const int4*>(deg + base);
    const int s = v.x + v.y + v.z + v.w;
    int inc = s;
#pragma unroll
    for (int off = 1; off < 64; off <<= 1) {
        const int u = __shfl_up(inc, off);
        if (lane >= off) inc += u;
    }
    __shared__ int wsum[4];
    if (lane == 63) wsum[wv] = inc;
    __syncthreads();
    int add = boff[b];
    for (int w = 0; w < wv; ++w) add += wsum[w];
    const int exc = add + inc - s;
    if (base < N_NODES) rowp[base] = exc;
    if (base + 1 < N_NODES) rowp[base + 1] = exc + v.x;
    if (base + 2 < N_NODES) rowp[base + 2] = exc + v.x + v.y;
    if (base + 3 < N_NODES) rowp[base + 3] = exc + v.x + v.y + v.z;
}

// ---------------- binned scatter; stage entry = src(16b) | local(8b)<<16 -----
__global__ void __launch_bounds__(256) k_bin(const int* __restrict__ src,
                                             const int* __restrict__ dst,
                                             const int* __restrict__ rowp,
                                             int* __restrict__ bfill,
                                             unsigned int* __restrict__ stage) {
    __shared__ int lcnt[NBKT];
    __shared__ int gb[NBKT];
    __shared__ int lf[NBKT];
    const int t = threadIdx.x;
    const int e0 = blockIdx.x * EPB_BIN;
    for (int i = t; i < NBKT; i += 256) lcnt[i] = 0;
    __syncthreads();
    int dcache[16];
#pragma unroll
    for (int i = 0; i < 16; ++i) {
        const int e = e0 + i * 256 + t;
        if (e < N_EDGES) {
            const int d = dst[e];
            dcache[i] = d;
            atomicAdd(&lcnt[d >> 8], 1);
        } else dcache[i] = -1;
    }
    __syncthreads();
    for (int i = t; i < NBKT; i += 256) {
        gb[i] = rowp[i << 8] + atomicAdd(&bfill[i], lcnt[i]);
        lf[i] = 0;
    }
    __syncthreads();
#pragma unroll
    for (int i = 0; i < 16; ++i) {
        const int e = e0 + i * 256 + t;
        if (e < N_EDGES) {
            const int d = dcache[i];
            const int b = d >> 8;
            const int r = atomicAdd(&lf[b], 1);
            stage[gb[b] + r] = (unsigned int)src[e] | ((unsigned int)(d & 255) << 16);
        }
    }
}

__global__ void __launch_bounds__(256) k_bscatter(const unsigned int* __restrict__ stage,
                                                  const int* __restrict__ rowp,
                                                  int* __restrict__ col) {
    __shared__ int srow[257];
    __shared__ int lf[256];
    const int t = threadIdx.x;
    const int n0 = blockIdx.x << 8;
    for (int i = t; i < 257; i += 256) srow[i] = rowp[min(n0 + i, N_NODES)];
    lf[t] = 0;
    __syncthreads();
    const int base = srow[0], end = srow[256];
    for (int j = base + t; j < end; j += 256) {
        const unsigned int e = stage[j];
        const int local = (int)(e >> 16) & 255;
        const int pos = srow[local] + atomicAdd(&lf[local], 1);
        col[pos] = (int)(e & 0xFFFFu);
    }
}

// ---------------- el/er: el[n][h] = sum_k x[n,k]*Wa[k][h]; float4 [N][4] -----
template <int K, int F, typename XT>
__global__ void __launch_bounds__(256) k_el(const XT* __restrict__ x,
                                            const float* __restrict__ W,
                                            const float* __restrict__ al,
                                            const float* __restrict__ ar,
                                            float* __restrict__ el,
                                            float* __restrict__ er) {
    __shared__ float sWa[K * 3];
    __shared__ float sWr[K * 3];
    const int t = threadIdx.x;
    if (t < 3 * K) {
        const int h = t / K, k = t % K;
        float sa = 0.f, sr = 0.f;
        for (int f = 0; f < F; ++f) {
            const float w = W[k * 3 * F + h * F + f];
            sa += w * al[h * F + f];
            sr += w * ar[h * F + f];
        }
        sWa[k * 3 + h] = sa;
        sWr[k * 3 + h] = sr;
    }
    __syncthreads();
    const int n = blockIdx.x * 256 + t;
    if (n >= N_NODES) return;
    const XT* __restrict__ xr = x + (size_t)n * K;
    float a0 = 0.f, a1 = 0.f, a2 = 0.f, r0 = 0.f, r1 = 0.f, r2 = 0.f;
#pragma unroll 4
    for (int k = 0; k < K; ++k) {
        const float xv = to_f(xr[k]);
        a0 += xv * sWa[k * 3 + 0];
        a1 += xv * sWa[k * 3 + 1];
        a2 += xv * sWa[k * 3 + 2];
        r0 += xv * sWr[k * 3 + 0];
        r1 += xv * sWr[k * 3 + 1];
        r2 += xv * sWr[k * 3 + 2];
    }
    *reinterpret_cast<float4*>(el + (size_t)n * 4) = make_float4(a0, a1, a2, 0.f);
    *reinterpret_cast<float4*>(er + (size_t)n * 4) = make_float4(r0, r1, r2, 0.f);
}

// ---------------- L1 aggregation over INPUT features (K=9, fp32) -------------
__global__ void __launch_bounds__(256) k_aggw9(const float* __restrict__ x,
                                               const float* __restrict__ el,
                                               const float* __restrict__ er,
                                               const int* __restrict__ rowp,
                                               const int* __restrict__ col,
                                               float* __restrict__ agg) {
    const int wv = threadIdx.x >> 6;
    const int lane = threadIdx.x & 63;
    const int n = blockIdx.x * 4 + wv;          // grid exact
    const int jb = rowp[n], je = rowp[n + 1];

    __shared__ float wbuf[4][3][68];
    const float4 er4 = *reinterpret_cast<const float4*>(er + (size_t)n * 4);
    const int h = lane < 27 ? lane / 9 : 0;
    const int k = lane < 27 ? lane % 9 : 0;
    float acc = 0.f;
    float sw0 = 0.f, sw1 = 0.f, sw2 = 0.f;

    for (int c0 = jb; c0 < je; c0 += 64) {
        const int cnt = min(64, je - c0);
        float w0 = 0.f, w1 = 0.f, w2 = 0.f;
        if (lane < cnt) {
            const int s = col[c0 + lane];
            const float4 e4 = *reinterpret_cast<const float4*>(el + (size_t)s * 4);
            w0 = __expf(lrelu(e4.x + er4.x));
            w1 = __expf(lrelu(e4.y + er4.y));
            w2 = __expf(lrelu(e4.z + er4.z));
            wbuf[wv][0][lane] = w0;
            wbuf[wv][1][lane] = w1;
            wbuf[wv][2][lane] = w2;
        }
        sw0 += w0; sw1 += w1; sw2 += w2;
        if (lane < 27) {
            const float* __restrict__ wrow = &wbuf[wv][h][0];
            int e = 0;
            for (; e + 4 <= cnt; e += 4) {
                const int sA = __builtin_amdgcn_readfirstlane(col[c0 + e + 0]);
                const int sB = __builtin_amdgcn_readfirstlane(col[c0 + e + 1]);
                const int sC = __builtin_amdgcn_readfirstlane(col[c0 + e + 2]);
                const int sD = __builtin_amdgcn_readfirstlane(col[c0 + e + 3]);
                const float xA = x[(size_t)sA * 9 + k];
                const float xB = x[(size_t)sB * 9 + k];
                const float xC = x[(size_t)sC * 9 + k];
                const float xD = x[(size_t)sD * 9 + k];
                acc += wrow[e + 0] * xA + wrow[e + 1] * xB
                     + wrow[e + 2] * xC + wrow[e + 3] * xD;
            }
            for (; e < cnt; ++e) {
                const int s = __builtin_amdgcn_readfirstlane(col[c0 + e]);
                acc += wrow[e] * x[(size_t)s * 9 + k];
            }
        }
    }
#pragma unroll
    for (int off = 32; off > 0; off >>= 1) {
        sw0 += __shfl_xor(sw0, off);
        sw1 += __shfl_xor(sw1, off);
        sw2 += __shfl_xor(sw2, off);
    }
    if (lane < 27) {
        const float swh = (h == 0) ? sw0 : (h == 1 ? sw1 : sw2);
        agg[(size_t)n * 28 + lane] = (je > jb) ? acc / swh : 0.f;
    }
    if (lane == 27) agg[(size_t)n * 28 + 27] = 0.f;
}

// ---------------- L2 aggregation: 2 edges/gather (half-wave per edge) --------
__global__ void __launch_bounds__(256) k_aggw64(const __half* __restrict__ x,
                                                const float* __restrict__ el,
                                                const float* __restrict__ er,
                                                const int* __restrict__ rowp,
                                                const int* __restrict__ col,
                                                __half* __restrict__ agg) {
    const int wv = threadIdx.x >> 6;
    const int lane = threadIdx.x & 63;
    const int n = blockIdx.x * 4 + wv;          // grid exact
    const int jb = rowp[n], je = rowp[n + 1];

    __shared__ float wbuf[4][3][68];
    __shared__ int cbuf[4][68];
    const float4 er4 = *reinterpret_cast<const float4*>(er + (size_t)n * 4);
    const int p = lane >> 5;                    // edge parity
    const int f0 = (lane & 31) * 2;             // feature pair base
    float a00 = 0.f, a01 = 0.f, a02 = 0.f;
    float a10 = 0.f, a11 = 0.f, a12 = 0.f;
    float sw0 = 0.f, sw1 = 0.f, sw2 = 0.f;

    for (int c0 = jb; c0 < je; c0 += 64) {
        const int cnt = min(64, je - c0);
        float w0 = 0.f, w1 = 0.f, w2 = 0.f;
        if (lane < cnt) {
            const int s = col[c0 + lane];
            cbuf[wv][lane] = s;
            const float4 e4 = *reinterpret_cast<const float4*>(el + (size_t)s * 4);
            w0 = __expf(lrelu(e4.x + er4.x));
            w1 = __expf(lrelu(e4.y + er4.y));
            w2 = __expf(lrelu(e4.z + er4.z));
            wbuf[wv][0][lane] = w0;
            wbuf[wv][1][lane] = w1;
            wbuf[wv][2][lane] = w2;
        }
        sw0 += w0; sw1 += w1; sw2 += w2;
        int e = 0;
        for (; e + 2 <= cnt; e += 2) {
            const int ei = e + p;
            const int s = cbuf[wv][ei];
            const float2 xv = __half22float2(
                *reinterpret_cast<const __half2*>(x + (size_t)s * 64 + f0));
            const float we0 = wbuf[wv][0][ei];
            const float we1 = wbuf[wv][1][ei];
            const float we2 = wbuf[wv][2][ei];
            a00 += we0 * xv.x; a01 += we1 * xv.x; a02 += we2 * xv.x;
            a10 += we0 * xv.y; a11 += we1 * xv.y; a12 += we2 * xv.y;
        }
        if (e < cnt && p == 0) {               // odd tail: lanes 0..31 only
            const int s = cbuf[wv][e];
            const float2 xv = __half22float2(
                *reinterpret_cast<const __half2*>(x + (size_t)s * 64 + f0));
            const float we0 = wbuf[wv][0][e];
            const float we1 = wbuf[wv][1][e];
            const float we2 = wbuf[wv][2][e];
            a00 += we0 * xv.x; a01 += we1 * xv.x; a02 += we2 * xv.x;
            a10 += we0 * xv.y; a11 += we1 * xv.y; a12 += we2 * xv.y;
        }
    }
    a00 += __shfl_xor(a00, 32); a01 += __shfl_xor(a01, 32); a02 += __shfl_xor(a02, 32);
    a10 += __shfl_xor(a10, 32); a11 += __shfl_xor(a11, 32); a12 += __shfl_xor(a12, 32);
#pragma unroll
    for (int off = 32; off > 0; off >>= 1) {
        sw0 += __shfl_xor(sw0, off);
        sw1 += __shfl_xor(sw1, off);
        sw2 += __shfl_xor(sw2, off);
    }
    if (lane < 32) {
        __half* __restrict__ ao = agg + (size_t)n * 192;
        if (je > jb) {
            const float i0 = 1.f / sw0, i1 = 1.f / sw1, i2 = 1.f / sw2;
            *reinterpret_cast<__half2*>(ao + f0) =
                __floats2half2_rn(a00 * i0, a10 * i0);
            *reinterpret_cast<__half2*>(ao + 64 + f0) =
                __floats2half2_rn(a01 * i1, a11 * i1);
            *reinterpret_cast<__half2*>(ao + 128 + f0) =
                __floats2half2_rn(a02 * i2, a12 * i2);
        } else {
            const __half2 z = __floats2half2_rn(0.f, 0.f);
            *reinterpret_cast<__half2*>(ao + f0) = z;
            *reinterpret_cast<__half2*>(ao + 64 + f0) = z;
            *reinterpret_cast<__half2*>(ao + 128 + f0) = z;
        }
    }
}

// ---------------- post-agg GEMM (fp32 agg, layer 1) --------------------------
template <int KE, int AS, int HOFF>
__global__ void __launch_bounds__(192) k_gemm2(const float* __restrict__ agg,
                                               const float* __restrict__ W,
                                               const float* __restrict__ bias,
                                               __half* __restrict__ hout) {
    const int NPB = 16;
    const int h = threadIdx.x >> 6;
    const int c = threadIdx.x & 63;
    float wreg[KE];
#pragma unroll
    for (int k = 0; k < KE; ++k) wreg[k] = W[k * 192 + h * 64 + c];

    __shared__ float At[NPB * AS];
    __shared__ float part[3][NPB][64];
    const int nbase = blockIdx.x * NPB;         // 3125 * 16 = 50000 exact

    const float4* __restrict__ src4 =
        reinterpret_cast<const float4*>(agg + (size_t)nbase * AS);
    float4* At4 = reinterpret_cast<float4*>(At);
    for (int idx = threadIdx.x; idx < NPB * AS / 4; idx += 192) At4[idx] = src4[idx];
    __syncthreads();

#pragma unroll
    for (int i = 0; i < NPB; ++i) {
        const float* __restrict__ ar = At + i * AS + h * HOFF;
        float acc = 0.f;
#pragma unroll
        for (int k = 0; k < KE; ++k) acc += ar[k] * wreg[k];
        part[h][i][c] = acc;
    }
    __syncthreads();
    for (int idx = threadIdx.x; idx < NPB * 64; idx += 192) {
        const int i = idx >> 6, cc = idx & 63;
        const float v = part[0][i][cc] + part[1][i][cc] + part[2][i][cc]
                      + bias[cc] + bias[64 + cc] + bias[128 + cc];
        hout[(size_t)(nbase + i) * 64 + cc] = __float2half(v);
    }
}

// ---------------- layer-2 GEMM, register-tiled: W in LDS, 2x4 thread tile ----
// C[32n x 64c] = A[32 x 192 fp16] @ Weff[192][64], Weff[h*64+k'][c]=W[k'][192h..]
// A row stride 194 halves (97 dwords, odd) -> per-instruction A reads are
// 4-address broadcasts (conflict-free). W stride 64 -> 2-way (free).
__global__ void __launch_bounds__(256) k_gemm3(const __half* __restrict__ agg,
                                               const float* __restrict__ W,
                                               const float* __restrict__ bias,
                                               __half* __restrict__ hout) {
    __shared__ __half Ash[32 * 194];        // 12416 B
    __shared__ float Wl[192 * 64];          // 49152 B  (total 60.1 KB)
    const int t = threadIdx.x;
    const int tx = t & 15;                  // output quad: c = tx*4..+3
    const int ty = t >> 4;                  // node pair: m = ty*2, ty*2+1
    const int nbase = blockIdx.x * 32;
    const int nvalid = min(32, N_NODES - nbase);

    // stage Weff: Wl[ke*64+c] = W[(ke&63)*192 + (ke>>6)*64 + c]  (coalesced)
    {
        const int c = t & 63;
        for (int ke = t >> 6; ke < 192; ke += 4)
            Wl[ke * 64 + c] = W[(ke & 63) * 192 + (ke >> 6) * 64 + c];
    }
    // stage A tile: 24 uint4 per node row
    {
        const uint4* __restrict__ src =
            reinterpret_cast<const uint4*>(agg + (size_t)nbase * 192);
        const int total = nvalid * 24;
        for (int idx = t; idx < total; idx += 256) {
            const int m = idx / 24, pos = idx % 24;
            const uint4 q = src[idx];
            unsigned int* dst =
                reinterpret_cast<unsigned int*>(Ash + m * 194 + pos * 8);
            dst[0] = q.x; dst[1] = q.y; dst[2] = q.z; dst[3] = q.w;
        }
    }
    __syncthreads();

    float acc[2][4];
#pragma unroll
    for (int i = 0; i < 2; ++i)
#pragma unroll
        for (int j = 0; j < 4; ++j) acc[i][j] = 0.f;

#pragma unroll 2
    for (int k = 0; k < 192; k += 2) {
        const float4 w0 = *reinterpret_cast<const float4*>(Wl + k * 64 + tx * 4);
        const float4 w1 = *reinterpret_cast<const float4*>(Wl + (k + 1) * 64 + tx * 4);
#pragma unroll
        for (int i = 0; i < 2; ++i) {
            const float2 a = __half22float2(
                *reinterpret_cast<const __half2*>(Ash + (ty * 2 + i) * 194 + k));
            acc[i][0] += a.x * w0.x + a.y * w1.x;
            acc[i][1] += a.x * w0.y + a.y * w1.y;
            acc[i][2] += a.x * w0.z + a.y * w1.z;
            acc[i][3] += a.x * w0.w + a.y * w1.w;
        }
    }

    const int c0 = tx * 4;
    const float4 bA = *reinterpret_cast<const float4*>(bias + c0);
    const float4 bB = *reinterpret_cast<const float4*>(bias + 64 + c0);
    const float4 bC = *reinterpret_cast<const float4*>(bias + 128 + c0);
    const float4 bs = make_float4(bA.x + bB.x + bC.x, bA.y + bB.y + bC.y,
                                  bA.z + bB.z + bC.z, bA.w + bB.w + bC.w);
#pragma unroll
    for (int i = 0; i < 2; ++i) {
        const int m = ty * 2 + i;
        if (m < nvalid) {
            __half2* o = reinterpret_cast<__half2*>(hout + (size_t)(nbase + m) * 64 + c0);
            o[0] = __floats2half2_rn(acc[i][0] + bs.x, acc[i][1] + bs.y);
            o[1] = __floats2half2_rn(acc[i][2] + bs.z, acc[i][3] + bs.w);
        }
    }
}

// ---------------- layer 3: feat3 = h @ W3 (64->6), h is fp16 -----------------
__global__ void __launch_bounds__(256) k_feat3(const __half* __restrict__ x,
                                               const float* __restrict__ W3,
                                               float* __restrict__ feat3) {
    __shared__ float Wl[64 * 6];
    __shared__ float xl[32 * 64];
    const int t = threadIdx.x;
    const int n0 = blockIdx.x * 32;
    const int nvalid = min(32, N_NODES - n0);
    for (int idx = t; idx < 384; idx += 256) Wl[idx] = W3[idx];
    for (int idx = t; idx < nvalid * 64; idx += 256)
        xl[idx] = __half2float(x[(size_t)n0 * 64 + idx]);
    __syncthreads();

    const int i = t >> 3;
    const int slot = t & 7;
    if (i < nvalid && slot < 6) {
        float acc = 0.f;
#pragma unroll
        for (int k4 = 0; k4 < 16; ++k4) {
            const float4 xv = *reinterpret_cast<const float4*>(&xl[i * 64 + 4 * k4]);
            acc += Wl[(4 * k4 + 0) * 6 + slot] * xv.x;
            acc += Wl[(4 * k4 + 1) * 6 + slot] * xv.y;
            acc += Wl[(4 * k4 + 2) * 6 + slot] * xv.z;
            acc += Wl[(4 * k4 + 3) * 6 + slot] * xv.w;
        }
        feat3[(size_t)(n0 + i) * 8 + slot] = acc;
    }
}

// ---------------- layer-3 aggregation: 8 lanes/node, inline weights ----------
__global__ void __launch_bounds__(256) k_agg3(const float* __restrict__ feat3,
                                              const float* __restrict__ el3,
                                              const float* __restrict__ er3,
                                              const float* __restrict__ b3,
                                              const int* __restrict__ rowp,
                                              const int* __restrict__ col,
                                              float* __restrict__ out) {
    const int t = blockIdx.x * blockDim.x + threadIdx.x;
    const int n = t >> 3;
    const int r = t & 7;       // feature slot (0..5 valid; head = r/2)
    if (n >= N_NODES) return;
    int hh = r >> 1; if (hh > 2) hh = 2;
    const float ern = er3[(size_t)n * 4 + hh];
    const int jb = rowp[n], je = rowp[n + 1];
    float a = 0.f, sw = 0.f;
    for (int j = jb; j < je; ++j) {
        const int s = col[j];
        const float w = __expf(lrelu(el3[(size_t)s * 4 + hh] + ern));
        const float f = feat3[(size_t)s * 8 + r];
        a += w * f;
        sw += w;
    }
    float v = (je > jb && r < 6) ? (a / sw) : 0.f;
    v += __shfl_down(v, 2, 8);
    v += __shfl_down(v, 4, 8);
    if (r < 2) {
        const float bc = b3[r] + b3[r + 2] + b3[r + 4];
        out[(size_t)n * 2 + r] = v + bc;
    }
}

extern "C" void kernel_launch(void* const* d_in, const int* in_sizes, int n_in,
                              void* d_out, int out_size, void* d_ws, size_t ws_size,
                              hipStream_t stream) {
    const float* feats = (const float*)d_in[0];
    const int* src = (const int*)d_in[1];
    const int* dst = (const int*)d_in[2];
    const float* W1 = (const float*)d_in[3];
    const float* al1 = (const float*)d_in[4];
    const float* ar1 = (const float*)d_in[5];
    const float* b1 = (const float*)d_in[6];
    const float* W2 = (const float*)d_in[7];
    const float* al2 = (const float*)d_in[8];
    const float* ar2 = (const float*)d_in[9];
    const float* b2 = (const float*)d_in[10];
    const float* W3 = (const float*)d_in[11];
    const float* al3 = (const float*)d_in[12];
    const float* ar3 = (const float*)d_in[13];
    const float* b3 = (const float*)d_in[14];
    float* out = (float*)d_out;

    char* ws = (char*)d_ws;
    size_t off = 0;
    auto alloc = [&](size_t bytes) {
        void* p = ws + off;
        off += (bytes + 255) & ~(size_t)255;
        return p;
    };
    float* agg = (float*)alloc((size_t)N_NODES * 28 * 4);        // L1 agg fp32 [N][28]
    __half* aggH = (__half*)alloc((size_t)N_NODES * 192 * 2);    // L2 agg fp16 [N][192]
    __half* hbufH = (__half*)alloc((size_t)N_NODES * 64 * 2);    // 6.4 MB fp16 hidden
    float* el = (float*)alloc((size_t)N_NODES * 4 * 4);
    float* er = (float*)alloc((size_t)N_NODES * 4 * 4);
    int* deg = (int*)alloc(((size_t)DEG_PAD + 256) * 4);         // deg + bfill, one memset
    int* bfill = deg + DEG_PAD;
    int* rowp = (int*)alloc((size_t)(N_NODES + 1) * 4);
    int* col = (int*)alloc((size_t)N_EDGES * 4);
    unsigned int* stage = (unsigned int*)alloc((size_t)N_EDGES * 4);  // packed 3.2 MB
    int* bsum = (int*)alloc(64 * 4);
    int* boff = (int*)alloc(64 * 4);
    float* feat3 = (float*)alloc((size_t)N_NODES * 8 * 4);
    (void)ws_size;

    // ---- CSR build ----
    hipMemsetAsync(deg, 0, ((size_t)DEG_PAD + 256) * 4, stream);
    int eb = (N_EDGES + 255) / 256;
    k_count<<<eb, 256, 0, stream>>>(dst, deg);
    k_scanA<<<NB_SCAN, 256, 0, stream>>>(deg, bsum);
    k_scanB<<<1, 64, 0, stream>>>(bsum, boff, rowp);
    k_scanC<<<NB_SCAN, 256, 0, stream>>>(deg, boff, rowp);
    k_bin<<<NB_BIN, 256, 0, stream>>>(src, dst, rowp, bfill, stage);
    k_bscatter<<<NBKT, 256, 0, stream>>>(stage, rowp, col);

    const int ab = N_NODES / 4;             // wave/node kernels: 4 waves/block
    const int gb2 = N_NODES / 16;           // k_gemm2: 16 nodes/block (3125)
    const int gb3 = (N_NODES + 31) / 32;    // k_gemm3: 32 nodes/block (1563)
    const int nb = (N_NODES + 255) / 256;
    const int nb3 = (N_NODES + 31) / 32;

    // ---- layer 1: aggregate INPUT features (1.8 MB table), then GEMM -------
    k_el<9, 64, float><<<nb, 256, 0, stream>>>(feats, W1, al1, ar1, el, er);
    k_aggw9<<<ab, 256, 0, stream>>>(feats, el, er, rowp, col, agg);
    k_gemm2<9, 28, 9><<<gb2, 192, 0, stream>>>(agg, W1, b1, hbufH);

    // ---- layer 2: aggregate fp16 hidden (6.4 MB table), then tiled GEMM ----
    k_el<64, 64, __half><<<nb, 256, 0, stream>>>(hbufH, W2, al2, ar2, el, er);
    k_aggw64<<<ab, 256, 0, stream>>>(hbufH, el, er, rowp, col, aggH);
    k_gemm3<<<gb3, 256, 0, stream>>>(aggH, W2, b2, hbufH);

    // ---- layer 3 ----
    k_el<64, 2, __half><<<nb, 256, 0, stream>>>(hbufH, W3, al3, ar3, el, er);
    k_feat3<<<nb3, 256, 0, stream>>>(hbufH, W3, feat3);
    k_agg3<<<nb3, 256, 0, stream>>>(feat3, el, er, b3, rowp, col, out);
}

// Round 17
// 298.847 us; speedup vs baseline: 1.1315x; 1.0558x over previous
//
#include <hip/hip_runtime.h>
#include <hip/hip_fp16.h>

#define N_NODES 50000
#define N_EDGES 800000
#define NB_SCAN 49          // ceil(50000 / 1024)
#define DEG_PAD (NB_SCAN * 1024)   // 50176, zero-padded so int4 loads are unguarded
#define NBKT 196            // ceil(50000 / 256) coarse buckets (dst >> 8)
#define EPB_BIN 4096        // edges per k_bin block
#define NB_BIN ((N_EDGES + EPB_BIN - 1) / EPB_BIN)   // 196

typedef _Float16 half8 __attribute__((ext_vector_type(8)));
typedef float f32x4 __attribute__((ext_vector_type(4)));

static __device__ __forceinline__ float lrelu(float x) { return fmaxf(x, 0.2f * x); }
static __device__ __forceinline__ float to_f(float x) { return x; }
static __device__ __forceinline__ float to_f(__half x) { return __half2float(x); }

// ---------------- CSR build ----------------
__global__ void k_count(const int* __restrict__ dst, int* __restrict__ deg) {
    int e = blockIdx.x * blockDim.x + threadIdx.x;
    if (e < N_EDGES) atomicAdd(&deg[dst[e]], 1);
}

__global__ void __launch_bounds__(256) k_scanA(const int* __restrict__ deg,
                                               int* __restrict__ bsum) {
    const int t = threadIdx.x;
    const int b = blockIdx.x;
    const int base = (b * 256 + t) * 4;
    const int4 v = *reinterpret_cast<const int4*>(deg + base);  // padded: safe
    int s = v.x + v.y + v.z + v.w;
#pragma unroll
    for (int off = 32; off > 0; off >>= 1) s += __shfl_down(s, off);
    __shared__ int ws[4];
    if ((t & 63) == 0) ws[t >> 6] = s;
    __syncthreads();
    if (t == 0) bsum[b] = ws[0] + ws[1] + ws[2] + ws[3];
}

__global__ void __launch_bounds__(64) k_scanB(const int* __restrict__ bsum,
                                              int* __restrict__ boff,
                                              int* __restrict__ rowp) {
    const int t = threadIdx.x;
    const int v = (t < NB_SCAN) ? bsum[t] : 0;
    int inc = v;
#pragma unroll
    for (int off = 1; off < 64; off <<= 1) {
        const int u = __shfl_up(inc, off);
        if (t >= off) inc += u;
    }
    if (t < NB_SCAN) boff[t] = inc - v;
    if (t == 0) rowp[N_NODES] = N_EDGES;
}

__global__ void __launch_bounds__(256) k_scanC(const int* __restrict__ deg,
                                               const int* __restrict__ boff,
                                               int* __restrict__ rowp) {
    const int t = threadIdx.x;
    const int b = blockIdx.x;
    const int lane = t & 63;
    const int wv = t >> 6;
    const int base = (b * 256 + t) * 4;
    const int4 v = *reinterpret_cast<const int4*>(deg + base);
    const int s = v.x + v.y + v.z + v.w;
    int inc = s;
#pragma unroll
    for (int off = 1; off < 64; off <<= 1) {
        const int u = __shfl_up(inc, off);
        if (lane >= off) inc += u;
    }
    __shared__ int wsum[4];
    if (lane == 63) wsum[wv] = inc;
    __syncthreads();
    int add = boff[b];
    for (int w = 0; w < wv; ++w) add += wsum[w];
    const int exc = add + inc - s;
    if (base < N_NODES) rowp[base] = exc;
    if (base + 1 < N_NODES) rowp[base + 1] = exc + v.x;
    if (base + 2 < N_NODES) rowp[base + 2] = exc + v.x + v.y;
    if (base + 3 < N_NODES) rowp[base + 3] = exc + v.x + v.y + v.z;
}

// ---------------- binned scatter; stage entry = src(16b) | local(8b)<<16 -----
__global__ void __launch_bounds__(256) k_bin(const int* __restrict__ src,
                                             const int* __restrict__ dst,
                                             const int* __restrict__ rowp,
                                             int* __restrict__ bfill,
                                             unsigned int* __restrict__ stage) {
    __shared__ int lcnt[NBKT];
    __shared__ int gb[NBKT];
    __shared__ int lf[NBKT];
    const int t = threadIdx.x;
    const int e0 = blockIdx.x * EPB_BIN;
    for (int i = t; i < NBKT; i += 256) lcnt[i] = 0;
    __syncthreads();
    int dcache[16];
#pragma unroll
    for (int i = 0; i < 16; ++i) {
        const int e = e0 + i * 256 + t;
        if (e < N_EDGES) {
            const int d = dst[e];
            dcache[i] = d;
            atomicAdd(&lcnt[d >> 8], 1);
        } else dcache[i] = -1;
    }
    __syncthreads();
    for (int i = t; i < NBKT; i += 256) {
        gb[i] = rowp[i << 8] + atomicAdd(&bfill[i], lcnt[i]);
        lf[i] = 0;
    }
    __syncthreads();
#pragma unroll
    for (int i = 0; i < 16; ++i) {
        const int e = e0 + i * 256 + t;
        if (e < N_EDGES) {
            const int d = dcache[i];
            const int b = d >> 8;
            const int r = atomicAdd(&lf[b], 1);
            stage[gb[b] + r] = (unsigned int)src[e] | ((unsigned int)(d & 255) << 16);
        }
    }
}

__global__ void __launch_bounds__(256) k_bscatter(const unsigned int* __restrict__ stage,
                                                  const int* __restrict__ rowp,
                                                  int* __restrict__ col) {
    __shared__ int srow[257];
    __shared__ int lf[256];
    const int t = threadIdx.x;
    const int n0 = blockIdx.x << 8;
    for (int i = t; i < 257; i += 256) srow[i] = rowp[min(n0 + i, N_NODES)];
    lf[t] = 0;
    __syncthreads();
    const int base = srow[0], end = srow[256];
    for (int j = base + t; j < end; j += 256) {
        const unsigned int e = stage[j];
        const int local = (int)(e >> 16) & 255;
        const int pos = srow[local] + atomicAdd(&lf[local], 1);
        col[pos] = (int)(e & 0xFFFFu);
    }
}

// ---------------- el/er: el[n][h] = sum_k x[n,k]*Wa[k][h]; float4 [N][4] -----
template <int K, int F, typename XT>
__global__ void __launch_bounds__(256) k_el(const XT* __restrict__ x,
                                            const float* __restrict__ W,
                                            const float* __restrict__ al,
                                            const float* __restrict__ ar,
                                            float* __restrict__ el,
                                            float* __restrict__ er) {
    __shared__ float sWa[K * 3];
    __shared__ float sWr[K * 3];
    const int t = threadIdx.x;
    if (t < 3 * K) {
        const int h = t / K, k = t % K;
        float sa = 0.f, sr = 0.f;
        for (int f = 0; f < F; ++f) {
            const float w = W[k * 3 * F + h * F + f];
            sa += w * al[h * F + f];
            sr += w * ar[h * F + f];
        }
        sWa[k * 3 + h] = sa;
        sWr[k * 3 + h] = sr;
    }
    __syncthreads();
    const int n = blockIdx.x * 256 + t;
    if (n >= N_NODES) return;
    const XT* __restrict__ xr = x + (size_t)n * K;
    float a0 = 0.f, a1 = 0.f, a2 = 0.f, r0 = 0.f, r1 = 0.f, r2 = 0.f;
#pragma unroll 4
    for (int k = 0; k < K; ++k) {
        const float xv = to_f(xr[k]);
        a0 += xv * sWa[k * 3 + 0];
        a1 += xv * sWa[k * 3 + 1];
        a2 += xv * sWa[k * 3 + 2];
        r0 += xv * sWr[k * 3 + 0];
        r1 += xv * sWr[k * 3 + 1];
        r2 += xv * sWr[k * 3 + 2];
    }
    *reinterpret_cast<float4*>(el + (size_t)n * 4) = make_float4(a0, a1, a2, 0.f);
    *reinterpret_cast<float4*>(er + (size_t)n * 4) = make_float4(r0, r1, r2, 0.f);
}

// ---------------- L1 aggregation over INPUT features (K=9, fp32) -------------
__global__ void __launch_bounds__(256) k_aggw9(const float* __restrict__ x,
                                               const float* __restrict__ el,
                                               const float* __restrict__ er,
                                               const int* __restrict__ rowp,
                                               const int* __restrict__ col,
                                               float* __restrict__ agg) {
    const int wv = threadIdx.x >> 6;
    const int lane = threadIdx.x & 63;
    const int n = blockIdx.x * 4 + wv;          // grid exact
    const int jb = rowp[n], je = rowp[n + 1];

    __shared__ float wbuf[4][3][68];
    const float4 er4 = *reinterpret_cast<const float4*>(er + (size_t)n * 4);
    const int h = lane < 27 ? lane / 9 : 0;
    const int k = lane < 27 ? lane % 9 : 0;
    float acc = 0.f;
    float sw0 = 0.f, sw1 = 0.f, sw2 = 0.f;

    for (int c0 = jb; c0 < je; c0 += 64) {
        const int cnt = min(64, je - c0);
        float w0 = 0.f, w1 = 0.f, w2 = 0.f;
        if (lane < cnt) {
            const int s = col[c0 + lane];
            const float4 e4 = *reinterpret_cast<const float4*>(el + (size_t)s * 4);
            w0 = __expf(lrelu(e4.x + er4.x));
            w1 = __expf(lrelu(e4.y + er4.y));
            w2 = __expf(lrelu(e4.z + er4.z));
            wbuf[wv][0][lane] = w0;
            wbuf[wv][1][lane] = w1;
            wbuf[wv][2][lane] = w2;
        }
        sw0 += w0; sw1 += w1; sw2 += w2;
        if (lane < 27) {
            const float* __restrict__ wrow = &wbuf[wv][h][0];
            int e = 0;
            for (; e + 4 <= cnt; e += 4) {
                const int sA = __builtin_amdgcn_readfirstlane(col[c0 + e + 0]);
                const int sB = __builtin_amdgcn_readfirstlane(col[c0 + e + 1]);
                const int sC = __builtin_amdgcn_readfirstlane(col[c0 + e + 2]);
                const int sD = __builtin_amdgcn_readfirstlane(col[c0 + e + 3]);
                const float xA = x[(size_t)sA * 9 + k];
                const float xB = x[(size_t)sB * 9 + k];
                const float xC = x[(size_t)sC * 9 + k];
                const float xD = x[(size_t)sD * 9 + k];
                acc += wrow[e + 0] * xA + wrow[e + 1] * xB
                     + wrow[e + 2] * xC + wrow[e + 3] * xD;
            }
            for (; e < cnt; ++e) {
                const int s = __builtin_amdgcn_readfirstlane(col[c0 + e]);
                acc += wrow[e] * x[(size_t)s * 9 + k];
            }
        }
    }
#pragma unroll
    for (int off = 32; off > 0; off >>= 1) {
        sw0 += __shfl_xor(sw0, off);
        sw1 += __shfl_xor(sw1, off);
        sw2 += __shfl_xor(sw2, off);
    }
    if (lane < 27) {
        const float swh = (h == 0) ? sw0 : (h == 1 ? sw1 : sw2);
        agg[(size_t)n * 28 + lane] = (je > jb) ? acc / swh : 0.f;
    }
    if (lane == 27) agg[(size_t)n * 28 + 27] = 0.f;
}

// ---------------- L2 aggregation: 2 edges/gather (half-wave per edge) --------
__global__ void __launch_bounds__(256) k_aggw64(const __half* __restrict__ x,
                                                const float* __restrict__ el,
                                                const float* __restrict__ er,
                                                const int* __restrict__ rowp,
                                                const int* __restrict__ col,
                                                __half* __restrict__ agg) {
    const int wv = threadIdx.x >> 6;
    const int lane = threadIdx.x & 63;
    const int n = blockIdx.x * 4 + wv;          // grid exact
    const int jb = rowp[n], je = rowp[n + 1];

    __shared__ float wbuf[4][3][68];
    __shared__ int cbuf[4][68];
    const float4 er4 = *reinterpret_cast<const float4*>(er + (size_t)n * 4);
    const int p = lane >> 5;                    // edge parity
    const int f0 = (lane & 31) * 2;             // feature pair base
    float a00 = 0.f, a01 = 0.f, a02 = 0.f;
    float a10 = 0.f, a11 = 0.f, a12 = 0.f;
    float sw0 = 0.f, sw1 = 0.f, sw2 = 0.f;

    for (int c0 = jb; c0 < je; c0 += 64) {
        const int cnt = min(64, je - c0);
        float w0 = 0.f, w1 = 0.f, w2 = 0.f;
        if (lane < cnt) {
            const int s = col[c0 + lane];
            cbuf[wv][lane] = s;
            const float4 e4 = *reinterpret_cast<const float4*>(el + (size_t)s * 4);
            w0 = __expf(lrelu(e4.x + er4.x));
            w1 = __expf(lrelu(e4.y + er4.y));
            w2 = __expf(lrelu(e4.z + er4.z));
            wbuf[wv][0][lane] = w0;
            wbuf[wv][1][lane] = w1;
            wbuf[wv][2][lane] = w2;
        }
        sw0 += w0; sw1 += w1; sw2 += w2;
        int e = 0;
        for (; e + 2 <= cnt; e += 2) {
            const int ei = e + p;
            const int s = cbuf[wv][ei];
            const float2 xv = __half22float2(
                *reinterpret_cast<const __half2*>(x + (size_t)s * 64 + f0));
            const float we0 = wbuf[wv][0][ei];
            const float we1 = wbuf[wv][1][ei];
            const float we2 = wbuf[wv][2][ei];
            a00 += we0 * xv.x; a01 += we1 * xv.x; a02 += we2 * xv.x;
            a10 += we0 * xv.y; a11 += we1 * xv.y; a12 += we2 * xv.y;
        }
        if (e < cnt && p == 0) {               // odd tail: lanes 0..31 only
            const int s = cbuf[wv][e];
            const float2 xv = __half22float2(
                *reinterpret_cast<const __half2*>(x + (size_t)s * 64 + f0));
            const float we0 = wbuf[wv][0][e];
            const float we1 = wbuf[wv][1][e];
            const float we2 = wbuf[wv][2][e];
            a00 += we0 * xv.x; a01 += we1 * xv.x; a02 += we2 * xv.x;
            a10 += we0 * xv.y; a11 += we1 * xv.y; a12 += we2 * xv.y;
        }
    }
    a00 += __shfl_xor(a00, 32); a01 += __shfl_xor(a01, 32); a02 += __shfl_xor(a02, 32);
    a10 += __shfl_xor(a10, 32); a11 += __shfl_xor(a11, 32); a12 += __shfl_xor(a12, 32);
#pragma unroll
    for (int off = 32; off > 0; off >>= 1) {
        sw0 += __shfl_xor(sw0, off);
        sw1 += __shfl_xor(sw1, off);
        sw2 += __shfl_xor(sw2, off);
    }
    if (lane < 32) {
        __half* __restrict__ ao = agg + (size_t)n * 192;
        if (je > jb) {
            const float i0 = 1.f / sw0, i1 = 1.f / sw1, i2 = 1.f / sw2;
            *reinterpret_cast<__half2*>(ao + f0) =
                __floats2half2_rn(a00 * i0, a10 * i0);
            *reinterpret_cast<__half2*>(ao + 64 + f0) =
                __floats2half2_rn(a01 * i1, a11 * i1);
            *reinterpret_cast<__half2*>(ao + 128 + f0) =
                __floats2half2_rn(a02 * i2, a12 * i2);
        } else {
            const __half2 z = __floats2half2_rn(0.f, 0.f);
            *reinterpret_cast<__half2*>(ao + f0) = z;
            *reinterpret_cast<__half2*>(ao + 64 + f0) = z;
            *reinterpret_cast<__half2*>(ao + 128 + f0) = z;
        }
    }
}

// ---------------- post-agg GEMM (fp32 agg, layer 1) --------------------------
template <int KE, int AS, int HOFF>
__global__ void __launch_bounds__(192) k_gemm2(const float* __restrict__ agg,
                                               const float* __restrict__ W,
                                               const float* __restrict__ bias,
                                               __half* __restrict__ hout) {
    const int NPB = 16;
    const int h = threadIdx.x >> 6;
    const int c = threadIdx.x & 63;
    float wreg[KE];
#pragma unroll
    for (int k = 0; k < KE; ++k) wreg[k] = W[k * 192 + h * 64 + c];

    __shared__ float At[NPB * AS];
    __shared__ float part[3][NPB][64];
    const int nbase = blockIdx.x * NPB;         // 3125 * 16 = 50000 exact

    const float4* __restrict__ src4 =
        reinterpret_cast<const float4*>(agg + (size_t)nbase * AS);
    float4* At4 = reinterpret_cast<float4*>(At);
    for (int idx = threadIdx.x; idx < NPB * AS / 4; idx += 192) At4[idx] = src4[idx];
    __syncthreads();

#pragma unroll
    for (int i = 0; i < NPB; ++i) {
        const float* __restrict__ ar = At + i * AS + h * HOFF;
        float acc = 0.f;
#pragma unroll
        for (int k = 0; k < KE; ++k) acc += ar[k] * wreg[k];
        part[h][i][c] = acc;
    }
    __syncthreads();
    for (int idx = threadIdx.x; idx < NPB * 64; idx += 192) {
        const int i = idx >> 6, cc = idx & 63;
        const float v = part[0][i][cc] + part[1][i][cc] + part[2][i][cc]
                      + bias[cc] + bias[64 + cc] + bias[128 + cc];
        hout[(size_t)(nbase + i) * 64 + cc] = __float2half(v);
    }
}

// ---------------- W2 -> fp16 effective-transpose table Wt16[n][192] ----------
// Wt16[n*192 + ke] = W[(ke&63)*192 + (ke>>6)*64 + n]   (24 KB, L2-resident)
__global__ void __launch_bounds__(256) k_prepW(const float* __restrict__ W,
                                               __half* __restrict__ Wt16) {
    const int idx = blockIdx.x * 256 + threadIdx.x;
    if (idx >= 64 * 192) return;
    const int n = idx / 192, ke = idx % 192;
    Wt16[idx] = __float2half(W[(ke & 63) * 192 + (ke >> 6) * 64 + n]);
}

// ---------------- layer-2 GEMM via MFMA, fragment-direct from global --------
// Wave: 16 nodes x 64 cols, K=192 = 6 x mfma_f32_16x16x32_f16 per 16x16 tile.
// A = aggH [node][192] fp16 (frag A[m=lane&15][k=quad*8+j] -> contiguous 16B).
// B = Wt16 [n][192] fp16 (B^T layout, frag B[n=lane&15][k=quad*8+j]).
// D: col=lane&15, row=quad*4+reg.  No LDS, no barriers.
__global__ void __launch_bounds__(256) k_gemm3m(const __half* __restrict__ agg,
                                                const __half* __restrict__ Wt,
                                                const float* __restrict__ bias,
                                                __half* __restrict__ hout) {
    const int wv = threadIdx.x >> 6;
    const int lane = threadIdx.x & 63;
    const int quad = lane >> 4;
    const int t16 = lane & 15;
    const int nwave = blockIdx.x * 64 + wv * 16;      // first node of this wave

    const int arow = min(nwave + t16, N_NODES - 1);   // clamp; writes guarded
    half8 a[6];
#pragma unroll
    for (int kb = 0; kb < 6; ++kb)
        a[kb] = *reinterpret_cast<const half8*>(agg + (size_t)arow * 192 + kb * 32 + quad * 8);

    float bs[4];
#pragma unroll
    for (int nt = 0; nt < 4; ++nt) {
        const int c = nt * 16 + t16;
        bs[nt] = bias[c] + bias[64 + c] + bias[128 + c];
    }

#pragma unroll
    for (int nt = 0; nt < 4; ++nt) {
        const __half* __restrict__ bt = Wt + (size_t)(nt * 16 + t16) * 192 + quad * 8;
        f32x4 acc = {0.f, 0.f, 0.f, 0.f};
#pragma unroll
        for (int kb = 0; kb < 6; ++kb) {
            const half8 b = *reinterpret_cast<const half8*>(bt + kb * 32);
            acc = __builtin_amdgcn_mfma_f32_16x16x32_f16(a[kb], b, acc, 0, 0, 0);
        }
        const int c = nt * 16 + t16;
#pragma unroll
        for (int r = 0; r < 4; ++r) {
            const int node = nwave + quad * 4 + r;
            if (node < N_NODES)
                hout[(size_t)node * 64 + c] = __float2half(acc[r] + bs[nt]);
        }
    }
}

// ---------------- layer 3: feat3 = h @ W3 (64->6), h is fp16 -----------------
__global__ void __launch_bounds__(256) k_feat3(const __half* __restrict__ x,
                                               const float* __restrict__ W3,
                                               float* __restrict__ feat3) {
    __shared__ float Wl[64 * 6];
    __shared__ float xl[32 * 64];
    const int t = threadIdx.x;
    const int n0 = blockIdx.x * 32;
    const int nvalid = min(32, N_NODES - n0);
    for (int idx = t; idx < 384; idx += 256) Wl[idx] = W3[idx];
    for (int idx = t; idx < nvalid * 64; idx += 256)
        xl[idx] = __half2float(x[(size_t)n0 * 64 + idx]);
    __syncthreads();

    const int i = t >> 3;
    const int slot = t & 7;
    if (i < nvalid && slot < 6) {
        float acc = 0.f;
#pragma unroll
        for (int k4 = 0; k4 < 16; ++k4) {
            const float4 xv = *reinterpret_cast<const float4*>(&xl[i * 64 + 4 * k4]);
            acc += Wl[(4 * k4 + 0) * 6 + slot] * xv.x;
            acc += Wl[(4 * k4 + 1) * 6 + slot] * xv.y;
            acc += Wl[(4 * k4 + 2) * 6 + slot] * xv.z;
            acc += Wl[(4 * k4 + 3) * 6 + slot] * xv.w;
        }
        feat3[(size_t)(n0 + i) * 8 + slot] = acc;
    }
}

// ---------------- layer-3 aggregation: 8 lanes/node, inline weights ----------
__global__ void __launch_bounds__(256) k_agg3(const float* __restrict__ feat3,
                                              const float* __restrict__ el3,
                                              const float* __restrict__ er3,
                                              const float* __restrict__ b3,
                                              const int* __restrict__ rowp,
                                              const int* __restrict__ col,
                                              float* __restrict__ out) {
    const int t = blockIdx.x * blockDim.x + threadIdx.x;
    const int n = t >> 3;
    const int r = t & 7;       // feature slot (0..5 valid; head = r/2)
    if (n >= N_NODES) return;
    int hh = r >> 1; if (hh > 2) hh = 2;
    const float ern = er3[(size_t)n * 4 + hh];
    const int jb = rowp[n], je = rowp[n + 1];
    float a = 0.f, sw = 0.f;
    for (int j = jb; j < je; ++j) {
        const int s = col[j];
        const float w = __expf(lrelu(el3[(size_t)s * 4 + hh] + ern));
        const float f = feat3[(size_t)s * 8 + r];
        a += w * f;
        sw += w;
    }
    float v = (je > jb && r < 6) ? (a / sw) : 0.f;
    v += __shfl_down(v, 2, 8);
    v += __shfl_down(v, 4, 8);
    if (r < 2) {
        const float bc = b3[r] + b3[r + 2] + b3[r + 4];
        out[(size_t)n * 2 + r] = v + bc;
    }
}

extern "C" void kernel_launch(void* const* d_in, const int* in_sizes, int n_in,
                              void* d_out, int out_size, void* d_ws, size_t ws_size,
                              hipStream_t stream) {
    const float* feats = (const float*)d_in[0];
    const int* src = (const int*)d_in[1];
    const int* dst = (const int*)d_in[2];
    const float* W1 = (const float*)d_in[3];
    const float* al1 = (const float*)d_in[4];
    const float* ar1 = (const float*)d_in[5];
    const float* b1 = (const float*)d_in[6];
    const float* W2 = (const float*)d_in[7];
    const float* al2 = (const float*)d_in[8];
    const float* ar2 = (const float*)d_in[9];
    const float* b2 = (const float*)d_in[10];
    const float* W3 = (const float*)d_in[11];
    const float* al3 = (const float*)d_in[12];
    const float* ar3 = (const float*)d_in[13];
    const float* b3 = (const float*)d_in[14];
    float* out = (float*)d_out;

    char* ws = (char*)d_ws;
    size_t off = 0;
    auto alloc = [&](size_t bytes) {
        void* p = ws + off;
        off += (bytes + 255) & ~(size_t)255;
        return p;
    };
    float* agg = (float*)alloc((size_t)N_NODES * 28 * 4);        // L1 agg fp32 [N][28]
    __half* aggH = (__half*)alloc((size_t)N_NODES * 192 * 2);    // L2 agg fp16 [N][192]
    __half* hbufH = (__half*)alloc((size_t)N_NODES * 64 * 2);    // 6.4 MB fp16 hidden
    float* el = (float*)alloc((size_t)N_NODES * 4 * 4);
    float* er = (float*)alloc((size_t)N_NODES * 4 * 4);
    int* deg = (int*)alloc(((size_t)DEG_PAD + 256) * 4);         // deg + bfill, one memset
    int* bfill = deg + DEG_PAD;
    int* rowp = (int*)alloc((size_t)(N_NODES + 1) * 4);
    int* col = (int*)alloc((size_t)N_EDGES * 4);
    unsigned int* stage = (unsigned int*)alloc((size_t)N_EDGES * 4);  // packed 3.2 MB
    int* bsum = (int*)alloc(64 * 4);
    int* boff = (int*)alloc(64 * 4);
    __half* Wt16 = (__half*)alloc((size_t)64 * 192 * 2);         // 24 KB fp16 W2^T
    float* feat3 = (float*)alloc((size_t)N_NODES * 8 * 4);
    (void)ws_size;

    // ---- CSR build ----
    hipMemsetAsync(deg, 0, ((size_t)DEG_PAD + 256) * 4, stream);
    int eb = (N_EDGES + 255) / 256;
    k_count<<<eb, 256, 0, stream>>>(dst, deg);
    k_scanA<<<NB_SCAN, 256, 0, stream>>>(deg, bsum);
    k_scanB<<<1, 64, 0, stream>>>(bsum, boff, rowp);
    k_scanC<<<NB_SCAN, 256, 0, stream>>>(deg, boff, rowp);
    k_bin<<<NB_BIN, 256, 0, stream>>>(src, dst, rowp, bfill, stage);
    k_bscatter<<<NBKT, 256, 0, stream>>>(stage, rowp, col);
    k_prepW<<<48, 256, 0, stream>>>(W2, Wt16);   // overlaps CSR build path

    const int ab = N_NODES / 4;             // wave/node kernels: 4 waves/block
    const int gb2 = N_NODES / 16;           // k_gemm2: 16 nodes/block (3125)
    const int gbm = (N_NODES + 63) / 64;    // k_gemm3m: 64 nodes/block (782)
    const int nb = (N_NODES + 255) / 256;
    const int nb3 = (N_NODES + 31) / 32;

    // ---- layer 1: aggregate INPUT features (1.8 MB table), then GEMM -------
    k_el<9, 64, float><<<nb, 256, 0, stream>>>(feats, W1, al1, ar1, el, er);
    k_aggw9<<<ab, 256, 0, stream>>>(feats, el, er, rowp, col, agg);
    k_gemm2<9, 28, 9><<<gb2, 192, 0, stream>>>(agg, W1, b1, hbufH);

    // ---- layer 2: aggregate fp16 hidden (6.4 MB table), then MFMA GEMM -----
    k_el<64, 64, __half><<<nb, 256, 0, stream>>>(hbufH, W2, al2, ar2, el, er);
    k_aggw64<<<ab, 256, 0, stream>>>(hbufH, el, er, rowp, col, aggH);
    k_gemm3m<<<gbm, 256, 0, stream>>>(aggH, Wt16, b2, hbufH);

    // ---- layer 3 ----
    k_el<64, 2, __half><<<nb, 256, 0, stream>>>(hbufH, W3, al3, ar3, el, er);
    k_feat3<<<nb3, 256, 0, stream>>>(hbufH, W3, feat3);
    k_agg3<<<nb3, 256, 0, stream>>>(feat3, el, er, b3, rowp, col, out);
}

// Round 18
// 271.598 us; speedup vs baseline: 1.2450x; 1.1003x over previous
//
#include <hip/hip_runtime.h>
#include <hip/hip_fp16.h>

#define N_NODES 50000
#define N_EDGES 800000
#define NBKT 196            // ceil(50000 / 256) coarse buckets (dst >> 8)
#define EPB_BIN 4096        // edges per binning block
#define NB_BIN ((N_EDGES + EPB_BIN - 1) / EPB_BIN)   // 196

typedef _Float16 half8 __attribute__((ext_vector_type(8)));
typedef float f32x4 __attribute__((ext_vector_type(4)));

static __device__ __forceinline__ float lrelu(float x) { return fmaxf(x, 0.2f * x); }
static __device__ __forceinline__ float to_f(float x) { return x; }
static __device__ __forceinline__ float to_f(__half x) { return __half2float(x); }

// ---------------- CSR build: bucket counts ----------------
__global__ void __launch_bounds__(256) k_cntb(const int* __restrict__ dst,
                                              int* __restrict__ bcnt) {
    __shared__ int lcnt[NBKT];
    const int t = threadIdx.x;
    const int e0 = blockIdx.x * EPB_BIN;
    for (int i = t; i < NBKT; i += 256) lcnt[i] = 0;
    __syncthreads();
#pragma unroll
    for (int i = 0; i < 16; ++i) {
        const int e = e0 + i * 256 + t;
        if (e < N_EDGES) atomicAdd(&lcnt[dst[e] >> 8], 1);
    }
    __syncthreads();
    for (int i = t; i < NBKT; i += 256)
        if (lcnt[i]) atomicAdd(&bcnt[i], lcnt[i]);
}

// exclusive scan of bucket counts -> bktbase[0..NBKT]
__global__ void __launch_bounds__(256) k_scanb(const int* __restrict__ bcnt,
                                               int* __restrict__ bktbase,
                                               int* __restrict__ rowp) {
    __shared__ int sh[256];
    const int t = threadIdx.x;
    const int v = (t < NBKT) ? bcnt[t] : 0;
    sh[t] = v;
    __syncthreads();
    for (int off = 1; off < 256; off <<= 1) {
        const int u = (t >= off) ? sh[t - off] : 0;
        __syncthreads();
        sh[t] += u;
        __syncthreads();
    }
    if (t < NBKT) bktbase[t] = sh[t] - v;
    if (t == 0) { bktbase[NBKT] = N_EDGES; rowp[N_NODES] = N_EDGES; }
}

// bin edges into bucket-contiguous stage; entry = src(16b) | local(8b)<<16
__global__ void __launch_bounds__(256) k_bin(const int* __restrict__ src,
                                             const int* __restrict__ dst,
                                             const int* __restrict__ bktbase,
                                             int* __restrict__ bfill,
                                             unsigned int* __restrict__ stage) {
    __shared__ int lcnt[NBKT];
    __shared__ int gb[NBKT];
    __shared__ int lf[NBKT];
    const int t = threadIdx.x;
    const int e0 = blockIdx.x * EPB_BIN;
    for (int i = t; i < NBKT; i += 256) lcnt[i] = 0;
    __syncthreads();
    int dcache[16];
#pragma unroll
    for (int i = 0; i < 16; ++i) {
        const int e = e0 + i * 256 + t;
        if (e < N_EDGES) {
            const int d = dst[e];
            dcache[i] = d;
            atomicAdd(&lcnt[d >> 8], 1);
        } else dcache[i] = -1;
    }
    __syncthreads();
    for (int i = t; i < NBKT; i += 256) {
        gb[i] = bktbase[i] + atomicAdd(&bfill[i], lcnt[i]);
        lf[i] = 0;
    }
    __syncthreads();
#pragma unroll
    for (int i = 0; i < 16; ++i) {
        const int e = e0 + i * 256 + t;
        if (e < N_EDGES) {
            const int d = dcache[i];
            const int b = d >> 8;
            const int r = atomicAdd(&lf[b], 1);
            stage[gb[b] + r] = (unsigned int)src[e] | ((unsigned int)(d & 255) << 16);
        }
    }
}

// per bucket: count nodes, scan -> rowp, place col
__global__ void __launch_bounds__(256) k_bscatter2(const unsigned int* __restrict__ stage,
                                                   const int* __restrict__ bktbase,
                                                   int* __restrict__ rowp,
                                                   int* __restrict__ col) {
    __shared__ int lcnt[256];
    __shared__ int lpos[256];
    __shared__ int sexc[256];
    const int t = threadIdx.x;
    const int b = blockIdx.x;
    const int n0 = b << 8;
    const int base = bktbase[b], end = bktbase[b + 1];
    lcnt[t] = 0;
    __syncthreads();
    for (int j = base + t; j < end; j += 256)
        atomicAdd(&lcnt[(stage[j] >> 16) & 255], 1);
    __syncthreads();
    const int v = lcnt[t];
    lpos[t] = v;
    __syncthreads();
    for (int off = 1; off < 256; off <<= 1) {
        const int u = (t >= off) ? lpos[t - off] : 0;
        __syncthreads();
        lpos[t] += u;
        __syncthreads();
    }
    sexc[t] = lpos[t] - v;
    if (n0 + t < N_NODES) rowp[n0 + t] = base + sexc[t];
    lcnt[t] = 0;   // reuse as fill counters
    __syncthreads();
    for (int j = base + t; j < end; j += 256) {
        const unsigned int e = stage[j];
        const int local = (int)(e >> 16) & 255;
        const int r = atomicAdd(&lcnt[local], 1);
        col[base + sexc[local] + r] = (int)(e & 0xFFFFu);
    }
}

// ---------------- el/er (layer 1): el[n][h] = sum_k x[n,k]*Wa[k][h] ----------
template <int K, int F, typename XT>
__global__ void __launch_bounds__(256) k_el(const XT* __restrict__ x,
                                            const float* __restrict__ W,
                                            const float* __restrict__ al,
                                            const float* __restrict__ ar,
                                            float* __restrict__ el,
                                            float* __restrict__ er) {
    __shared__ float sWa[K * 3];
    __shared__ float sWr[K * 3];
    const int t = threadIdx.x;
    if (t < 3 * K) {
        const int h = t / K, k = t % K;
        float sa = 0.f, sr = 0.f;
        for (int f = 0; f < F; ++f) {
            const float w = W[k * 3 * F + h * F + f];
            sa += w * al[h * F + f];
            sr += w * ar[h * F + f];
        }
        sWa[k * 3 + h] = sa;
        sWr[k * 3 + h] = sr;
    }
    __syncthreads();
    const int n = blockIdx.x * 256 + t;
    if (n >= N_NODES) return;
    const XT* __restrict__ xr = x + (size_t)n * K;
    float a0 = 0.f, a1 = 0.f, a2 = 0.f, r0 = 0.f, r1 = 0.f, r2 = 0.f;
#pragma unroll 4
    for (int k = 0; k < K; ++k) {
        const float xv = to_f(xr[k]);
        a0 += xv * sWa[k * 3 + 0];
        a1 += xv * sWa[k * 3 + 1];
        a2 += xv * sWa[k * 3 + 2];
        r0 += xv * sWr[k * 3 + 0];
        r1 += xv * sWr[k * 3 + 1];
        r2 += xv * sWr[k * 3 + 2];
    }
    *reinterpret_cast<float4*>(el + (size_t)n * 4) = make_float4(a0, a1, a2, 0.f);
    *reinterpret_cast<float4*>(er + (size_t)n * 4) = make_float4(r0, r1, r2, 0.f);
}

// ---------------- L1 aggregation, 2 edges/issue-group (parity) ---------------
// lanes 0..26: edge e (h=l2/9, k=l2%9); lanes 32..58: edge e+1.
__global__ void __launch_bounds__(256) k_aggw9(const float* __restrict__ x,
                                               const float* __restrict__ el,
                                               const float* __restrict__ er,
                                               const int* __restrict__ rowp,
                                               const int* __restrict__ col,
                                               float* __restrict__ agg) {
    const int wv = threadIdx.x >> 6;
    const int lane = threadIdx.x & 63;
    const int n = blockIdx.x * 4 + wv;          // grid exact
    const int jb = rowp[n], je = rowp[n + 1];

    __shared__ float wbuf[4][3][68];
    __shared__ int cbuf[4][68];
    const float4 er4 = *reinterpret_cast<const float4*>(er + (size_t)n * 4);
    const int p = lane >> 5;
    const int l2 = lane & 31;
    const bool act = l2 < 27;
    const int h = act ? l2 / 9 : 0;
    const int k = act ? l2 % 9 : 0;
    float acc = 0.f;
    float sw0 = 0.f, sw1 = 0.f, sw2 = 0.f;

    for (int c0 = jb; c0 < je; c0 += 64) {
        const int cnt = min(64, je - c0);
        float w0 = 0.f, w1 = 0.f, w2 = 0.f;
        if (lane < cnt) {
            const int s = col[c0 + lane];
            cbuf[wv][lane] = s;
            const float4 e4 = *reinterpret_cast<const float4*>(el + (size_t)s * 4);
            w0 = __expf(lrelu(e4.x + er4.x));
            w1 = __expf(lrelu(e4.y + er4.y));
            w2 = __expf(lrelu(e4.z + er4.z));
            wbuf[wv][0][lane] = w0;
            wbuf[wv][1][lane] = w1;
            wbuf[wv][2][lane] = w2;
        }
        sw0 += w0; sw1 += w1; sw2 += w2;
        int e = 0;
        for (; e + 4 <= cnt; e += 4) {
            const int s0 = cbuf[wv][e + p];
            const int s1 = cbuf[wv][e + 2 + p];
            const float we0 = wbuf[wv][h][e + p];
            const float we1 = wbuf[wv][h][e + 2 + p];
            const float x0 = x[(size_t)s0 * 9 + k];
            const float x1 = x[(size_t)s1 * 9 + k];
            if (act) acc += we0 * x0 + we1 * x1;
        }
        for (; e + 2 <= cnt; e += 2) {
            const int s0 = cbuf[wv][e + p];
            const float we0 = wbuf[wv][h][e + p];
            const float x0 = x[(size_t)s0 * 9 + k];
            if (act) acc += we0 * x0;
        }
        if (e < cnt && p == 0 && act) {
            const int s0 = cbuf[wv][e];
            acc += wbuf[wv][h][e] * x[(size_t)s0 * 9 + k];
        }
    }
    acc += __shfl_xor(acc, 32);
#pragma unroll
    for (int off = 32; off > 0; off >>= 1) {
        sw0 += __shfl_xor(sw0, off);
        sw1 += __shfl_xor(sw1, off);
        sw2 += __shfl_xor(sw2, off);
    }
    if (lane < 27) {
        const float swh = (h == 0) ? sw0 : (h == 1 ? sw1 : sw2);
        agg[(size_t)n * 28 + lane] = (je > jb) ? acc / swh : 0.f;
    }
    if (lane == 27) agg[(size_t)n * 28 + 27] = 0.f;
}

// ---------------- L2 aggregation: 2 edges/gather (unchanged, at roofline) ----
__global__ void __launch_bounds__(256) k_aggw64(const __half* __restrict__ x,
                                                const float* __restrict__ el,
                                                const float* __restrict__ er,
                                                const int* __restrict__ rowp,
                                                const int* __restrict__ col,
                                                __half* __restrict__ agg) {
    const int wv = threadIdx.x >> 6;
    const int lane = threadIdx.x & 63;
    const int n = blockIdx.x * 4 + wv;          // grid exact
    const int jb = rowp[n], je = rowp[n + 1];

    __shared__ float wbuf[4][3][68];
    __shared__ int cbuf[4][68];
    const float4 er4 = *reinterpret_cast<const float4*>(er + (size_t)n * 4);
    const int p = lane >> 5;
    const int f0 = (lane & 31) * 2;
    float a00 = 0.f, a01 = 0.f, a02 = 0.f;
    float a10 = 0.f, a11 = 0.f, a12 = 0.f;
    float sw0 = 0.f, sw1 = 0.f, sw2 = 0.f;

    for (int c0 = jb; c0 < je; c0 += 64) {
        const int cnt = min(64, je - c0);
        float w0 = 0.f, w1 = 0.f, w2 = 0.f;
        if (lane < cnt) {
            const int s = col[c0 + lane];
            cbuf[wv][lane] = s;
            const float4 e4 = *reinterpret_cast<const float4*>(el + (size_t)s * 4);
            w0 = __expf(lrelu(e4.x + er4.x));
            w1 = __expf(lrelu(e4.y + er4.y));
            w2 = __expf(lrelu(e4.z + er4.z));
            wbuf[wv][0][lane] = w0;
            wbuf[wv][1][lane] = w1;
            wbuf[wv][2][lane] = w2;
        }
        sw0 += w0; sw1 += w1; sw2 += w2;
        int e = 0;
        for (; e + 2 <= cnt; e += 2) {
            const int ei = e + p;
            const int s = cbuf[wv][ei];
            const float2 xv = __half22float2(
                *reinterpret_cast<const __half2*>(x + (size_t)s * 64 + f0));
            const float we0 = wbuf[wv][0][ei];
            const float we1 = wbuf[wv][1][ei];
            const float we2 = wbuf[wv][2][ei];
            a00 += we0 * xv.x; a01 += we1 * xv.x; a02 += we2 * xv.x;
            a10 += we0 * xv.y; a11 += we1 * xv.y; a12 += we2 * xv.y;
        }
        if (e < cnt && p == 0) {
            const int s = cbuf[wv][e];
            const float2 xv = __half22float2(
                *reinterpret_cast<const __half2*>(x + (size_t)s * 64 + f0));
            const float we0 = wbuf[wv][0][e];
            const float we1 = wbuf[wv][1][e];
            const float we2 = wbuf[wv][2][e];
            a00 += we0 * xv.x; a01 += we1 * xv.x; a02 += we2 * xv.x;
            a10 += we0 * xv.y; a11 += we1 * xv.y; a12 += we2 * xv.y;
        }
    }
    a00 += __shfl_xor(a00, 32); a01 += __shfl_xor(a01, 32); a02 += __shfl_xor(a02, 32);
    a10 += __shfl_xor(a10, 32); a11 += __shfl_xor(a11, 32); a12 += __shfl_xor(a12, 32);
#pragma unroll
    for (int off = 32; off > 0; off >>= 1) {
        sw0 += __shfl_xor(sw0, off);
        sw1 += __shfl_xor(sw1, off);
        sw2 += __shfl_xor(sw2, off);
    }
    if (lane < 32) {
        __half* __restrict__ ao = agg + (size_t)n * 192;
        if (je > jb) {
            const float i0 = 1.f / sw0, i1 = 1.f / sw1, i2 = 1.f / sw2;
            *reinterpret_cast<__half2*>(ao + f0) = __floats2half2_rn(a00 * i0, a10 * i0);
            *reinterpret_cast<__half2*>(ao + 64 + f0) = __floats2half2_rn(a01 * i1, a11 * i1);
            *reinterpret_cast<__half2*>(ao + 128 + f0) = __floats2half2_rn(a02 * i2, a12 * i2);
        } else {
            const __half2 z = __floats2half2_rn(0.f, 0.f);
            *reinterpret_cast<__half2*>(ao + f0) = z;
            *reinterpret_cast<__half2*>(ao + 64 + f0) = z;
            *reinterpret_cast<__half2*>(ao + 128 + f0) = z;
        }
    }
}

// ---------------- Wa2/Wr2 precompute (float4-packed [64][4]) -----------------
__global__ void __launch_bounds__(192) k_prepA(const float* __restrict__ W2,
                                               const float* __restrict__ al2,
                                               const float* __restrict__ ar2,
                                               float* __restrict__ Wa2,
                                               float* __restrict__ Wr2) {
    const int t = threadIdx.x;
    const int h = t >> 6, k = t & 63;
    float sa = 0.f, sr = 0.f;
    for (int f = 0; f < 64; ++f) {
        const float w = W2[k * 192 + h * 64 + f];
        sa += w * al2[h * 64 + f];
        sr += w * ar2[h * 64 + f];
    }
    Wa2[k * 4 + h] = sa;
    Wr2[k * 4 + h] = sr;
    if (h == 0) { Wa2[k * 4 + 3] = 0.f; Wr2[k * 4 + 3] = 0.f; }
}

// ---------------- layer-1 post-agg GEMM + fused el2/er2 ----------------------
template <int KE, int AS, int HOFF>
__global__ void __launch_bounds__(192) k_gemm2(const float* __restrict__ agg,
                                               const float* __restrict__ W,
                                               const float* __restrict__ bias,
                                               const float* __restrict__ Wa2,
                                               const float* __restrict__ Wr2,
                                               __half* __restrict__ hout,
                                               float* __restrict__ el,
                                               float* __restrict__ er) {
    const int NPB = 16;
    const int h = threadIdx.x >> 6;
    const int c = threadIdx.x & 63;
    float wreg[KE];
#pragma unroll
    for (int k = 0; k < KE; ++k) wreg[k] = W[k * 192 + h * 64 + c];

    __shared__ float At[NPB * AS];
    __shared__ float part[3][NPB][64];
    const int nbase = blockIdx.x * NPB;         // 3125 * 16 = 50000 exact

    const float4* __restrict__ src4 =
        reinterpret_cast<const float4*>(agg + (size_t)nbase * AS);
    float4* At4 = reinterpret_cast<float4*>(At);
    for (int idx = threadIdx.x; idx < NPB * AS / 4; idx += 192) At4[idx] = src4[idx];
    __syncthreads();

#pragma unroll
    for (int i = 0; i < NPB; ++i) {
        const float* __restrict__ ar = At + i * AS + h * HOFF;
        float acc = 0.f;
#pragma unroll
        for (int k = 0; k < KE; ++k) acc += ar[k] * wreg[k];
        part[h][i][c] = acc;
    }
    __syncthreads();
    const int lane = threadIdx.x & 63;          // == cc in the loop below
    const float4 wa = *reinterpret_cast<const float4*>(Wa2 + lane * 4);
    const float4 wr = *reinterpret_cast<const float4*>(Wr2 + lane * 4);
    for (int idx = threadIdx.x; idx < NPB * 64; idx += 192) {
        const int i = idx >> 6, cc = idx & 63;  // cc == lane (192 % 64 == 0)
        const float v = part[0][i][cc] + part[1][i][cc] + part[2][i][cc]
                      + bias[cc] + bias[64 + cc] + bias[128 + cc];
        hout[(size_t)(nbase + i) * 64 + cc] = __float2half(v);
        float e0 = v * wa.x, e1 = v * wa.y, e2 = v * wa.z;
        float r0 = v * wr.x, r1 = v * wr.y, r2 = v * wr.z;
#pragma unroll
        for (int off = 32; off > 0; off >>= 1) {
            e0 += __shfl_xor(e0, off); e1 += __shfl_xor(e1, off); e2 += __shfl_xor(e2, off);
            r0 += __shfl_xor(r0, off); r1 += __shfl_xor(r1, off); r2 += __shfl_xor(r2, off);
        }
        if (lane == 0) {
            *reinterpret_cast<float4*>(el + (size_t)(nbase + i) * 4) = make_float4(e0, e1, e2, 0.f);
            *reinterpret_cast<float4*>(er + (size_t)(nbase + i) * 4) = make_float4(r0, r1, r2, 0.f);
        }
    }
}

// ---------------- W2 -> fp16 effective-transpose table Wt16[n][192] ----------
__global__ void __launch_bounds__(256) k_prepW(const float* __restrict__ W,
                                               __half* __restrict__ Wt16) {
    const int idx = blockIdx.x * 256 + threadIdx.x;
    if (idx >= 64 * 192) return;
    const int n = idx / 192, ke = idx % 192;
    Wt16[idx] = __float2half(W[(ke & 63) * 192 + (ke >> 6) * 64 + n]);
}

// ---------------- layer-2 GEMM via MFMA, fragment-direct (unchanged) ---------
__global__ void __launch_bounds__(256) k_gemm3m(const __half* __restrict__ agg,
                                                const __half* __restrict__ Wt,
                                                const float* __restrict__ bias,
                                                __half* __restrict__ hout) {
    const int wv = threadIdx.x >> 6;
    const int lane = threadIdx.x & 63;
    const int quad = lane >> 4;
    const int t16 = lane & 15;
    const int nwave = blockIdx.x * 64 + wv * 16;

    const int arow = min(nwave + t16, N_NODES - 1);
    half8 a[6];
#pragma unroll
    for (int kb = 0; kb < 6; ++kb)
        a[kb] = *reinterpret_cast<const half8*>(agg + (size_t)arow * 192 + kb * 32 + quad * 8);

    float bs[4];
#pragma unroll
    for (int nt = 0; nt < 4; ++nt) {
        const int c = nt * 16 + t16;
        bs[nt] = bias[c] + bias[64 + c] + bias[128 + c];
    }

#pragma unroll
    for (int nt = 0; nt < 4; ++nt) {
        const __half* __restrict__ bt = Wt + (size_t)(nt * 16 + t16) * 192 + quad * 8;
        f32x4 acc = {0.f, 0.f, 0.f, 0.f};
#pragma unroll
        for (int kb = 0; kb < 6; ++kb) {
            const half8 b = *reinterpret_cast<const half8*>(bt + kb * 32);
            acc = __builtin_amdgcn_mfma_f32_16x16x32_f16(a[kb], b, acc, 0, 0, 0);
        }
        const int c = nt * 16 + t16;
#pragma unroll
        for (int r = 0; r < 4; ++r) {
            const int node = nwave + quad * 4 + r;
            if (node < N_NODES)
                hout[(size_t)node * 64 + c] = __float2half(acc[r] + bs[nt]);
        }
    }
}

// ---------------- layer 3: feat3 + fused el3/er3 -----------------------------
// xl padded to [32][68] (bank spread). 192 extra tasks compute el3/er3.
__global__ void __launch_bounds__(256) k_feat3(const __half* __restrict__ x,
                                               const float* __restrict__ W3,
                                               const float* __restrict__ al3,
                                               const float* __restrict__ ar3,
                                               float* __restrict__ feat3,
                                               float* __restrict__ el3,
                                               float* __restrict__ er3) {
    __shared__ float Wl[64 * 6];
    __shared__ float Wal[64 * 3];
    __shared__ float Wrl[64 * 3];
    __shared__ float xl[32 * 68];
    const int t = threadIdx.x;
    const int n0 = blockIdx.x * 32;
    const int nvalid = min(32, N_NODES - n0);
    for (int idx = t; idx < 384; idx += 256) Wl[idx] = W3[idx];
    if (t < 192) {
        const int k = t & 63, h = t >> 6;
        Wal[k * 3 + h] = W3[k * 6 + h * 2] * al3[h * 2] + W3[k * 6 + h * 2 + 1] * al3[h * 2 + 1];
        Wrl[k * 3 + h] = W3[k * 6 + h * 2] * ar3[h * 2] + W3[k * 6 + h * 2 + 1] * ar3[h * 2 + 1];
    }
    for (int idx = t; idx < nvalid * 64; idx += 256)
        xl[(idx >> 6) * 68 + (idx & 63)] = __half2float(x[(size_t)n0 * 64 + idx]);
    __syncthreads();

    const int i = t >> 3;
    const int slot = t & 7;
    if (i < nvalid && slot < 6) {
        float acc = 0.f;
#pragma unroll
        for (int k4 = 0; k4 < 16; ++k4) {
            const float4 xv = *reinterpret_cast<const float4*>(&xl[i * 68 + 4 * k4]);
            acc += Wl[(4 * k4 + 0) * 6 + slot] * xv.x;
            acc += Wl[(4 * k4 + 1) * 6 + slot] * xv.y;
            acc += Wl[(4 * k4 + 2) * 6 + slot] * xv.z;
            acc += Wl[(4 * k4 + 3) * 6 + slot] * xv.w;
        }
        feat3[(size_t)(n0 + i) * 8 + slot] = acc;
    }
    if (t < 192) {
        const int ii = t / 6, ss = t % 6;
        if (ii < nvalid) {
            const int hh = (ss < 3) ? ss : ss - 3;
            const float* __restrict__ wt = (ss < 3) ? Wal : Wrl;
            float acc = 0.f;
#pragma unroll 4
            for (int k = 0; k < 64; ++k) acc += xl[ii * 68 + k] * wt[k * 3 + hh];
            float* __restrict__ dstp = (ss < 3) ? el3 : er3;
            dstp[(size_t)(n0 + ii) * 4 + hh] = acc;
        }
    }
}

// ---------------- layer-3 aggregation: 8 lanes/node (unchanged) --------------
__global__ void __launch_bounds__(256) k_agg3(const float* __restrict__ feat3,
                                              const float* __restrict__ el3,
                                              const float* __restrict__ er3,
                                              const float* __restrict__ b3,
                                              const int* __restrict__ rowp,
                                              const int* __restrict__ col,
                                              float* __restrict__ out) {
    const int t = blockIdx.x * blockDim.x + threadIdx.x;
    const int n = t >> 3;
    const int r = t & 7;
    if (n >= N_NODES) return;
    int hh = r >> 1; if (hh > 2) hh = 2;
    const float ern = er3[(size_t)n * 4 + hh];
    const int jb = rowp[n], je = rowp[n + 1];
    float a = 0.f, sw = 0.f;
    for (int j = jb; j < je; ++j) {
        const int s = col[j];
        const float w = __expf(lrelu(el3[(size_t)s * 4 + hh] + ern));
        const float f = feat3[(size_t)s * 8 + r];
        a += w * f;
        sw += w;
    }
    float v = (je > jb && r < 6) ? (a / sw) : 0.f;
    v += __shfl_down(v, 2, 8);
    v += __shfl_down(v, 4, 8);
    if (r < 2) {
        const float bc = b3[r] + b3[r + 2] + b3[r + 4];
        out[(size_t)n * 2 + r] = v + bc;
    }
}

extern "C" void kernel_launch(void* const* d_in, const int* in_sizes, int n_in,
                              void* d_out, int out_size, void* d_ws, size_t ws_size,
                              hipStream_t stream) {
    const float* feats = (const float*)d_in[0];
    const int* src = (const int*)d_in[1];
    const int* dst = (const int*)d_in[2];
    const float* W1 = (const float*)d_in[3];
    const float* al1 = (const float*)d_in[4];
    const float* ar1 = (const float*)d_in[5];
    const float* b1 = (const float*)d_in[6];
    const float* W2 = (const float*)d_in[7];
    const float* al2 = (const float*)d_in[8];
    const float* ar2 = (const float*)d_in[9];
    const float* b2 = (const float*)d_in[10];
    const float* W3 = (const float*)d_in[11];
    const float* al3 = (const float*)d_in[12];
    const float* ar3 = (const float*)d_in[13];
    const float* b3 = (const float*)d_in[14];
    float* out = (float*)d_out;

    char* ws = (char*)d_ws;
    size_t off = 0;
    auto alloc = [&](size_t bytes) {
        void* p = ws + off;
        off += (bytes + 255) & ~(size_t)255;
        return p;
    };
    float* agg = (float*)alloc((size_t)N_NODES * 28 * 4);        // L1 agg fp32 [N][28]
    __half* aggH = (__half*)alloc((size_t)N_NODES * 192 * 2);    // L2 agg fp16 [N][192]
    __half* hbufH = (__half*)alloc((size_t)N_NODES * 64 * 2);    // fp16 hidden
    float* el = (float*)alloc((size_t)N_NODES * 4 * 4);
    float* er = (float*)alloc((size_t)N_NODES * 4 * 4);
    int* bcnt = (int*)alloc(512 * 4);                            // bcnt[256] + bfill[256]
    int* bfill = bcnt + 256;
    int* bktbase = (int*)alloc(256 * 4);
    int* rowp = (int*)alloc((size_t)(N_NODES + 1) * 4);
    int* col = (int*)alloc((size_t)N_EDGES * 4);
    unsigned int* stage = (unsigned int*)alloc((size_t)N_EDGES * 4);
    __half* Wt16 = (__half*)alloc((size_t)64 * 192 * 2);         // 24 KB fp16 W2^T
    float* Wa2 = (float*)alloc(256 * 4);
    float* Wr2 = (float*)alloc(256 * 4);
    float* feat3 = (float*)alloc((size_t)N_NODES * 8 * 4);
    (void)ws_size;

    // ---- CSR build (4 dispatches, no per-node atomic count pass) ----
    hipMemsetAsync(bcnt, 0, 512 * 4, stream);
    k_cntb<<<NB_BIN, 256, 0, stream>>>(dst, bcnt);
    k_scanb<<<1, 256, 0, stream>>>(bcnt, bktbase, rowp);
    k_bin<<<NB_BIN, 256, 0, stream>>>(src, dst, bktbase, bfill, stage);
    k_bscatter2<<<NBKT, 256, 0, stream>>>(stage, bktbase, rowp, col);
    k_prepW<<<48, 256, 0, stream>>>(W2, Wt16);
    k_prepA<<<1, 192, 0, stream>>>(W2, al2, ar2, Wa2, Wr2);

    const int ab = N_NODES / 4;             // wave/node kernels: 4 waves/block
    const int gb2 = N_NODES / 16;           // k_gemm2: 16 nodes/block
    const int gbm = (N_NODES + 63) / 64;    // k_gemm3m: 64 nodes/block
    const int nb = (N_NODES + 255) / 256;
    const int nb3 = (N_NODES + 31) / 32;

    // ---- layer 1 ----
    k_el<9, 64, float><<<nb, 256, 0, stream>>>(feats, W1, al1, ar1, el, er);
    k_aggw9<<<ab, 256, 0, stream>>>(feats, el, er, rowp, col, agg);
    k_gemm2<9, 28, 9><<<gb2, 192, 0, stream>>>(agg, W1, b1, Wa2, Wr2, hbufH, el, er);

    // ---- layer 2 (el2/er2 already produced by k_gemm2 epilogue) ----
    k_aggw64<<<ab, 256, 0, stream>>>(hbufH, el, er, rowp, col, aggH);
    k_gemm3m<<<gbm, 256, 0, stream>>>(aggH, Wt16, b2, hbufH);

    // ---- layer 3 (el3/er3 fused into k_feat3) ----
    k_feat3<<<nb3, 256, 0, stream>>>(hbufH, W3, al3, ar3, feat3, el, er);
    k_agg3<<<nb3, 256, 0, stream>>>(feat3, el, er, b3, rowp, col, out);
}